// Round 3
// baseline (385.632 us; speedup 1.0000x reference)
//
#include <hip/hip_runtime.h>
#include <cmath>

// Problem constants (from reference)
#define IN_DIM 128
#define HID 256
#define NHEADS 4
#define NGRAPHS 32

typedef unsigned short u16;

// bf16 helpers (RNE)
__device__ __forceinline__ u16 f2bf(float x) {
  unsigned u = __float_as_uint(x);
  unsigned r = (u + 0x7fffu + ((u >> 16) & 1u)) >> 16;
  return (u16)r;
}
__device__ __forceinline__ float bf2f(u16 v) {
  return __uint_as_float(((unsigned)v) << 16);
}

// ---------------------------------------------------------------------------
// CSR build: count incoming edges per dst, exclusive scan, fill src lists
// ---------------------------------------------------------------------------
__global__ __launch_bounds__(256) void count_edges_k(const int* __restrict__ dst,
                                                     int* __restrict__ cnt, int E) {
  int i = blockIdx.x * 256 + threadIdx.x;
  if (i < E) atomicAdd(&cnt[dst[i]], 1);
}

__global__ __launch_bounds__(1024) void scan_k(const int* __restrict__ cnt,
                                               int* __restrict__ row_ptr,
                                               float* __restrict__ dinv, int n) {
  __shared__ int sdata[1024];
  __shared__ int s_carry;
  if (threadIdx.x == 0) s_carry = 0;
  __syncthreads();
  int nchunks = (n + 1023) >> 10;
  for (int c = 0; c < nchunks; c++) {
    int i = (c << 10) + threadIdx.x;
    int v = (i < n) ? cnt[i] : 0;
    sdata[threadIdx.x] = v;
    __syncthreads();
    for (int off = 1; off < 1024; off <<= 1) {
      int t = (threadIdx.x >= off) ? sdata[threadIdx.x - off] : 0;
      __syncthreads();
      sdata[threadIdx.x] += t;
      __syncthreads();
    }
    int excl = sdata[threadIdx.x] - v;
    if (i < n) {
      row_ptr[i] = s_carry + excl;
      dinv[i] = rsqrtf((float)(v + 1));  // degree includes self-loop
    }
    __syncthreads();
    if (threadIdx.x == 0) s_carry += sdata[1023];
    __syncthreads();
  }
  if (threadIdx.x == 0) row_ptr[n] = s_carry;
}

__global__ __launch_bounds__(256) void fill_csr_k(const int* __restrict__ src,
                                                  const int* __restrict__ dst,
                                                  const int* __restrict__ row_ptr,
                                                  int* __restrict__ cursor,
                                                  int* __restrict__ csr_src, int E) {
  int i = blockIdx.x * 256 + threadIdx.x;
  if (i < E) {
    int d = dst[i];
    int p = atomicAdd(&cursor[d], 1);
    csr_src[row_ptr[d] + p] = src[i];
  }
}

// ---------------------------------------------------------------------------
// Tiled fp32 GEMM: C[M,N] = A[M,K] @ B[K,N].
// Templated on TM_: tile = (16*TM_) x 64, 256 threads, per-thread TM_ x 4.
// ---------------------------------------------------------------------------
#define BK 16
#define BN 64
#define TN 4

template <int TM_>
__global__ __launch_bounds__(256) void gemm_nn_k(const float* __restrict__ A,
                                                 const float* __restrict__ B,
                                                 float* __restrict__ C,
                                                 int M, int N, int K) {
  constexpr int BM = 16 * TM_;
  __shared__ float As[BK][BM + 4];
  __shared__ float Bs[BK][BN];
  int tid = threadIdx.x;
  int bm = blockIdx.y * BM;
  int bn = blockIdx.x * BN;
  int tx = tid & 15, ty = tid >> 4;
  float acc[TM_][TN] = {};
  for (int k0 = 0; k0 < K; k0 += BK) {
    #pragma unroll
    for (int it = 0; it < TM_ / 4; it++) {
      int f = tid + it * 256;
      int m = f >> 2;
      int k4 = f & 3;
      int gm = bm + m;
      float4 v = make_float4(0.f, 0.f, 0.f, 0.f);
      if (gm < M) v = *(const float4*)&A[(size_t)gm * K + k0 + k4 * 4];
      As[k4 * 4 + 0][m] = v.x;
      As[k4 * 4 + 1][m] = v.y;
      As[k4 * 4 + 2][m] = v.z;
      As[k4 * 4 + 3][m] = v.w;
    }
    {
      int kk = tid >> 4, n4 = tid & 15;
      *(float4*)&Bs[kk][n4 * 4] =
          *(const float4*)&B[(size_t)(k0 + kk) * N + bn + n4 * 4];
    }
    __syncthreads();
    #pragma unroll
    for (int kk = 0; kk < BK; kk++) {
      float a[TM_], b[TN];
      #pragma unroll
      for (int i = 0; i < TM_; i++) a[i] = As[kk][ty * TM_ + i];
      #pragma unroll
      for (int j = 0; j < TN; j++) b[j] = Bs[kk][tx * TN + j];
      #pragma unroll
      for (int i = 0; i < TM_; i++)
        #pragma unroll
        for (int j = 0; j < TN; j++) acc[i][j] += a[i] * b[j];
    }
    __syncthreads();
  }
  #pragma unroll
  for (int i = 0; i < TM_; i++) {
    int gm = bm + ty * TM_ + i;
    if (gm < M) {
      float4 v = make_float4(acc[i][0], acc[i][1], acc[i][2], acc[i][3]);
      *(float4*)&C[(size_t)gm * N + bn + tx * TN] = v;
    }
  }
}

// ---------------------------------------------------------------------------
// hg GEMM: hgT[h][m][c] (bf16, head-major) = A[M,256] @ Wg[256,1024]
// 128x64 tile, same inner loop as gemm_nn_k<8>, bf16 head-major epilogue.
// ---------------------------------------------------------------------------
__global__ __launch_bounds__(256) void gemm_hg_k(const float* __restrict__ A,
                                                 const float* __restrict__ B,
                                                 u16* __restrict__ hgT,
                                                 int M, int Nn) {
  constexpr int TM_ = 8;
  constexpr int BM = 128;
  const int N = NHEADS * HID;  // 1024
  const int K = HID;           // 256
  __shared__ float As[BK][BM + 4];
  __shared__ float Bs[BK][BN];
  int tid = threadIdx.x;
  int bm = blockIdx.y * BM;
  int bn = blockIdx.x * BN;
  int tx = tid & 15, ty = tid >> 4;
  float acc[TM_][TN] = {};
  for (int k0 = 0; k0 < K; k0 += BK) {
    #pragma unroll
    for (int it = 0; it < TM_ / 4; it++) {
      int f = tid + it * 256;
      int m = f >> 2;
      int k4 = f & 3;
      int gm = bm + m;
      float4 v = make_float4(0.f, 0.f, 0.f, 0.f);
      if (gm < M) v = *(const float4*)&A[(size_t)gm * K + k0 + k4 * 4];
      As[k4 * 4 + 0][m] = v.x;
      As[k4 * 4 + 1][m] = v.y;
      As[k4 * 4 + 2][m] = v.z;
      As[k4 * 4 + 3][m] = v.w;
    }
    {
      int kk = tid >> 4, n4 = tid & 15;
      *(float4*)&Bs[kk][n4 * 4] =
          *(const float4*)&B[(size_t)(k0 + kk) * N + bn + n4 * 4];
    }
    __syncthreads();
    #pragma unroll
    for (int kk = 0; kk < BK; kk++) {
      float a[TM_], b[TN];
      #pragma unroll
      for (int i = 0; i < TM_; i++) a[i] = As[kk][ty * TM_ + i];
      #pragma unroll
      for (int j = 0; j < TN; j++) b[j] = Bs[kk][tx * TN + j];
      #pragma unroll
      for (int i = 0; i < TM_; i++)
        #pragma unroll
        for (int j = 0; j < TN; j++) acc[i][j] += a[i] * b[j];
    }
    __syncthreads();
  }
  int gn = bn + tx * TN;      // column in [0,1024)
  int head = gn >> 8;         // all 4 cols in same head (bn % 64 == 0)
  int cc = gn & 255;
  #pragma unroll
  for (int i = 0; i < TM_; i++) {
    int gm = bm + ty * TM_ + i;
    if (gm < M) {
      ushort4 v;
      v.x = f2bf(acc[i][0]);
      v.y = f2bf(acc[i][1]);
      v.z = f2bf(acc[i][2]);
      v.w = f2bf(acc[i][3]);
      *(ushort4*)&hgT[((size_t)head * Nn + gm) * HID + cc] = v;
    }
  }
}

// ---------------------------------------------------------------------------
// GCN aggregation: out[i] = relu( sum_{s in N(i)} t[s]*dinv[s]*dinv[i]
//                                 + t[i]*dinv[i]^2 + b )
// ---------------------------------------------------------------------------
__global__ __launch_bounds__(256) void gcn_agg_k(const float* __restrict__ t,
                                                 const int* __restrict__ row_ptr,
                                                 const int* __restrict__ csr_src,
                                                 const float* __restrict__ dinv,
                                                 const float* __restrict__ bias,
                                                 float* __restrict__ out) {
  int i = blockIdx.x;
  int c = threadIdx.x;
  __shared__ int s_src[256];
  __shared__ float s_w[256];
  float di = dinv[i];
  float acc = t[(size_t)i * HID + c] * di * di;  // self loop
  int beg = row_ptr[i], end = row_ptr[i + 1];
  for (int base = beg; base < end; base += 256) {
    int m = min(256, end - base);
    if (c < m) {
      int s = csr_src[base + c];
      s_src[c] = s;
      s_w[c] = dinv[s] * di;
    }
    __syncthreads();
    for (int e = 0; e < m; e++) acc += t[(size_t)s_src[e] * HID + c] * s_w[e];
    __syncthreads();
  }
  out[(size_t)i * HID + c] = fmaxf(acc + bias[c], 0.f);
}

// ---------------------------------------------------------------------------
// Attention logit projections through the weights:
//   w_s[k][h] = sum_c Wg[k][h*256+c] * att_src[h][c]   (same for dst)
//   a_src[n][h] = sum_k h2[n][k] * w_s[k][h]
// ---------------------------------------------------------------------------
__global__ __launch_bounds__(256) void watt_k(const float* __restrict__ Wg,
                                              const float* __restrict__ att_src,
                                              const float* __restrict__ att_dst,
                                              float* __restrict__ w_s,
                                              float* __restrict__ w_d) {
  int k = threadIdx.x;  // 0..255
  #pragma unroll
  for (int h = 0; h < NHEADS; h++) {
    const float* wrow = Wg + (size_t)k * (NHEADS * HID) + h * HID;
    float ss = 0.f, dd = 0.f;
    for (int c = 0; c < HID; c++) {
      float w = wrow[c];
      ss += w * att_src[h * HID + c];
      dd += w * att_dst[h * HID + c];
    }
    w_s[k * NHEADS + h] = ss;
    w_d[k * NHEADS + h] = dd;
  }
}

__global__ __launch_bounds__(256) void att_proj_k(const float* __restrict__ h2,
                                                  const float* __restrict__ w_s,
                                                  const float* __restrict__ w_d,
                                                  float* __restrict__ a_src,
                                                  float* __restrict__ a_dst, int N) {
  __shared__ float lws[HID][NHEADS];
  __shared__ float lwd[HID][NHEADS];
  int t = threadIdx.x;
  #pragma unroll
  for (int h = 0; h < NHEADS; h++) {
    lws[t][h] = w_s[t * NHEADS + h];
    lwd[t][h] = w_d[t * NHEADS + h];
  }
  __syncthreads();
  int nl = t >> 2, h = t & 3;
  int n = blockIdx.x * 64 + nl;
  if (n >= N) return;
  const float* row = h2 + (size_t)n * HID;
  float as = 0.f, ad = 0.f;
  for (int k = 0; k < HID; k++) {
    float v = row[k];
    as += v * lws[k][h];
    ad += v * lwd[k][h];
  }
  a_src[n * NHEADS + h] = as;
  a_dst[n * NHEADS + h] = ad;
}

__device__ __forceinline__ float lrelu02(float x) { return x > 0.f ? x : 0.2f * x; }

// ---------------------------------------------------------------------------
// GAT aggregation, head-outer, bf16 head-major hgT gather.
// ---------------------------------------------------------------------------
__global__ __launch_bounds__(256) void gat_agg_k(const u16* __restrict__ hgT,
                                                 const int* __restrict__ row_ptr,
                                                 const int* __restrict__ csr_src,
                                                 const float* __restrict__ a_src,
                                                 const float* __restrict__ a_dst,
                                                 const float* __restrict__ bg,
                                                 float* __restrict__ out, int Nn) {
  int i = blockIdx.x;
  int t = threadIdx.x;
  int hw = t >> 6, lane = t & 63;
  __shared__ float s_m[NHEADS], s_iz[NHEADS];
  __shared__ int s_srcb[64];
  __shared__ float s_al[64];
  int beg = row_ptr[i], end = row_ptr[i + 1];
  float adst = a_dst[i * NHEADS + hw];

  // pass 1: max over edges + self-loop (wave hw owns head hw)
  float m = -INFINITY;
  for (int e = beg + lane; e < end; e += 64) {
    int s = csr_src[e];
    m = fmaxf(m, lrelu02(a_src[s * NHEADS + hw] + adst));
  }
  float vself = lrelu02(a_src[i * NHEADS + hw] + adst);
  m = fmaxf(m, vself);
  #pragma unroll
  for (int off = 32; off; off >>= 1) m = fmaxf(m, __shfl_xor(m, off));

  // pass 2: denom
  float z = 0.f;
  for (int e = beg + lane; e < end; e += 64) {
    int s = csr_src[e];
    z += expf(lrelu02(a_src[s * NHEADS + hw] + adst) - m);
  }
  if (lane == 0) z += expf(vself - m);
  #pragma unroll
  for (int off = 32; off; off >>= 1) z += __shfl_xor(z, off);
  if (lane == 0) {
    s_m[hw] = m;
    s_iz[hw] = 1.f / (z + 1e-16f);
  }
  __syncthreads();

  // pass 3: head-outer weighted gather; thread t = channel
  int c = t;
  float acc = 0.f;
  for (int h = 0; h < NHEADS; h++) {
    float mh = s_m[h], izh = s_iz[h];
    float adh = a_dst[i * NHEADS + h];
    const u16* slab = hgT + (size_t)h * Nn * HID;
    // self loop
    float aself = expf(lrelu02(a_src[i * NHEADS + h] + adh) - mh) * izh;
    float acch = aself * bf2f(slab[(size_t)i * HID + c]);
    for (int base = beg; base < end; base += 64) {
      int mc = min(64, end - base);
      if (t < mc) {
        int s = csr_src[base + t];
        s_srcb[t] = s;
        s_al[t] = expf(lrelu02(a_src[s * NHEADS + h] + adh) - mh) * izh;
      }
      __syncthreads();
      for (int e = 0; e < mc; e++)
        acch += s_al[e] * bf2f(slab[(size_t)s_srcb[e] * HID + c]);
      __syncthreads();
    }
    acc += acch;
  }
  out[(size_t)i * HID + c] = fmaxf(acc * 0.25f + bg[c], 0.f);
}

// ---------------------------------------------------------------------------
// Segmented global mean pool (batch sorted) + tiny head GEMM
// ---------------------------------------------------------------------------
#define POOL_CHUNK 50
__global__ __launch_bounds__(256) void pool_acc_k(const float* __restrict__ h3,
                                                  const int* __restrict__ batch,
                                                  float* __restrict__ pooled,
                                                  float* __restrict__ gcnt, int N) {
  int c = threadIdx.x;
  int i0 = blockIdx.x * POOL_CHUNK;
  int i1 = min(i0 + POOL_CHUNK, N);
  if (i0 >= N) return;
  float acc = 0.f;
  int cur = batch[i0];
  int cnt_local = 0;
  for (int i = i0; i < i1; i++) {
    int g = batch[i];
    if (g != cur) {
      atomicAdd(&pooled[cur * HID + c], acc);
      if (c == 0) atomicAdd(&gcnt[cur], (float)cnt_local);
      acc = 0.f;
      cnt_local = 0;
      cur = g;
    }
    acc += h3[(size_t)i * HID + c];
    cnt_local++;
  }
  atomicAdd(&pooled[cur * HID + c], acc);
  if (c == 0) atomicAdd(&gcnt[cur], (float)cnt_local);
}

__global__ __launch_bounds__(128) void head_k(const float* __restrict__ pooled,
                                              const float* __restrict__ gcnt,
                                              const float* __restrict__ W_heads,
                                              const float* __restrict__ b_heads,
                                              float* __restrict__ out) {
  int tid = threadIdx.x;
  if (tid >= NGRAPHS * 4) return;
  int g = tid >> 2, k = tid & 3;
  float invc = 1.f / fmaxf(gcnt[g], 1.f);
  float acc = 0.f;
  for (int c = 0; c < HID; c++) acc += pooled[g * HID + c] * W_heads[c * 4 + k];
  out[g * 4 + k] = acc * invc + b_heads[k];
}

// ---------------------------------------------------------------------------
extern "C" void kernel_launch(void* const* d_in, const int* in_sizes, int n_in,
                              void* d_out, int out_size, void* d_ws, size_t ws_size,
                              hipStream_t stream) {
  const float* x = (const float*)d_in[0];
  const int* ei = (const int*)d_in[1];
  const int* batch = (const int*)d_in[2];
  const float* W1 = (const float*)d_in[3];
  const float* b1 = (const float*)d_in[4];
  const float* W2 = (const float*)d_in[5];
  const float* b2 = (const float*)d_in[6];
  const float* Wg = (const float*)d_in[7];
  const float* att_src = (const float*)d_in[8];
  const float* att_dst = (const float*)d_in[9];
  const float* bg = (const float*)d_in[10];
  const float* W_heads = (const float*)d_in[11];
  const float* b_heads = (const float*)d_in[12];
  float* out = (float*)d_out;

  const int N = in_sizes[0] / IN_DIM;   // 10000
  const int E = in_sizes[1] / 2;        // 160000
  const int* src = ei;
  const int* dst = ei + E;

  // workspace layout (256B aligned)
  char* ws = (char*)d_ws;
  size_t off = 0;
  auto take = [&](size_t bytes) -> char* {
    char* p = ws + off;
    off = (off + bytes + 255) & ~(size_t)255;
    return p;
  };
  int* cnt      = (int*)take((size_t)N * 4);
  int* row_ptr  = (int*)take((size_t)(N + 1) * 4);
  int* cursor   = (int*)take((size_t)N * 4);
  int* csr_src  = (int*)take((size_t)E * 4);
  float* dinv   = (float*)take((size_t)N * 4);
  float* a_srcv = (float*)take((size_t)N * NHEADS * 4);
  float* a_dstv = (float*)take((size_t)N * NHEADS * 4);
  float* w_s    = (float*)take((size_t)HID * NHEADS * 4);
  float* w_d    = (float*)take((size_t)HID * NHEADS * 4);
  float* pooled = (float*)take((size_t)NGRAPHS * HID * 4 + NGRAPHS * 4);
  float* gcnt   = pooled + NGRAPHS * HID;
  float* t      = (float*)take((size_t)N * HID * 4);
  float* h1     = (float*)take((size_t)N * HID * 4);
  float* h2     = (float*)take((size_t)N * HID * 4);
  u16*   hgT    = (u16*)take((size_t)N * NHEADS * HID * 2);
  float* h3     = h1;  // alias: h1 dead after t2 = h1@W2

  hipMemsetAsync(cnt, 0, (size_t)N * 4, stream);
  hipMemsetAsync(cursor, 0, (size_t)N * 4, stream);
  hipMemsetAsync(pooled, 0, (size_t)NGRAPHS * HID * 4 + NGRAPHS * 4, stream);

  int eb = (E + 255) / 256;
  count_edges_k<<<eb, 256, 0, stream>>>(dst, cnt, E);
  scan_k<<<1, 1024, 0, stream>>>(cnt, row_ptr, dinv, N);
  fill_csr_k<<<eb, 256, 0, stream>>>(src, dst, row_ptr, cursor, csr_src, E);
  watt_k<<<1, 256, 0, stream>>>(Wg, att_src, att_dst, w_s, w_d);

  int mg64 = (N + 63) / 64;
  int mg128 = (N + 127) / 128;
  // layer 1: t = x @ W1 ; h1 = relu(agg(t) + b1)
  gemm_nn_k<4><<<dim3(HID / BN, mg64), 256, 0, stream>>>(x, W1, t, N, HID, IN_DIM);
  gcn_agg_k<<<N, 256, 0, stream>>>(t, row_ptr, csr_src, dinv, b1, h1);
  // layer 2: t = h1 @ W2 ; h2 = relu(agg(t) + b2)
  gemm_nn_k<4><<<dim3(HID / BN, mg64), 256, 0, stream>>>(h1, W2, t, N, HID, HID);
  gcn_agg_k<<<N, 256, 0, stream>>>(t, row_ptr, csr_src, dinv, b2, h2);
  // GAT: hgT (bf16, head-major) = h2 @ Wg ; logits via projected weights
  gemm_hg_k<<<dim3(NHEADS * HID / BN, mg128), 256, 0, stream>>>(h2, Wg, hgT, N, N);
  att_proj_k<<<mg64, 256, 0, stream>>>(h2, w_s, w_d, a_srcv, a_dstv, N);
  gat_agg_k<<<N, 256, 0, stream>>>(hgT, row_ptr, csr_src, a_srcv, a_dstv, bg, h3, N);
  // pool + heads
  int pb = (N + POOL_CHUNK - 1) / POOL_CHUNK;
  pool_acc_k<<<pb, 256, 0, stream>>>(h3, batch, pooled, gcnt, N);
  head_k<<<1, 128, 0, stream>>>(pooled, gcnt, W_heads, b_heads, out);
}

// Round 4
// 291.513 us; speedup vs baseline: 1.3229x; 1.3229x over previous
//
#include <hip/hip_runtime.h>
#include <cmath>

// Problem constants (from reference)
#define IN_DIM 128
#define HID 256
#define NHEADS 4
#define NGRAPHS 32

typedef unsigned short u16;

// bf16 helpers (RNE)
__device__ __forceinline__ u16 f2bf(float x) {
  unsigned u = __float_as_uint(x);
  unsigned r = (u + 0x7fffu + ((u >> 16) & 1u)) >> 16;
  return (u16)r;
}
__device__ __forceinline__ float bf2f(u16 v) {
  return __uint_as_float(((unsigned)v) << 16);
}

// ---------------------------------------------------------------------------
// CSR build: count incoming edges per dst, exclusive scan, fill src lists
// ---------------------------------------------------------------------------
__global__ __launch_bounds__(256) void count_edges_k(const int* __restrict__ dst,
                                                     int* __restrict__ cnt, int E) {
  int i = blockIdx.x * 256 + threadIdx.x;
  if (i < E) atomicAdd(&cnt[dst[i]], 1);
}

__global__ __launch_bounds__(1024) void scan_k(const int* __restrict__ cnt,
                                               int* __restrict__ row_ptr,
                                               float* __restrict__ dinv, int n) {
  __shared__ int sdata[1024];
  __shared__ int s_carry;
  if (threadIdx.x == 0) s_carry = 0;
  __syncthreads();
  int nchunks = (n + 1023) >> 10;
  for (int c = 0; c < nchunks; c++) {
    int i = (c << 10) + threadIdx.x;
    int v = (i < n) ? cnt[i] : 0;
    sdata[threadIdx.x] = v;
    __syncthreads();
    for (int off = 1; off < 1024; off <<= 1) {
      int t = (threadIdx.x >= off) ? sdata[threadIdx.x - off] : 0;
      __syncthreads();
      sdata[threadIdx.x] += t;
      __syncthreads();
    }
    int excl = sdata[threadIdx.x] - v;
    if (i < n) {
      row_ptr[i] = s_carry + excl;
      dinv[i] = rsqrtf((float)(v + 1));  // degree includes self-loop
    }
    __syncthreads();
    if (threadIdx.x == 0) s_carry += sdata[1023];
    __syncthreads();
  }
  if (threadIdx.x == 0) row_ptr[n] = s_carry;
}

__global__ __launch_bounds__(256) void fill_csr_k(const int* __restrict__ src,
                                                  const int* __restrict__ dst,
                                                  const int* __restrict__ row_ptr,
                                                  int* __restrict__ cursor,
                                                  int* __restrict__ csr_src, int E) {
  int i = blockIdx.x * 256 + threadIdx.x;
  if (i < E) {
    int d = dst[i];
    int p = atomicAdd(&cursor[d], 1);
    csr_src[row_ptr[d] + p] = src[i];
  }
}

// ---------------------------------------------------------------------------
// Tiled fp32 GEMM: C[M,N] = A[M,K] @ B[K,N].
// ---------------------------------------------------------------------------
#define BK 16
#define BN 64
#define TN 4

template <int TM_>
__global__ __launch_bounds__(256) void gemm_nn_k(const float* __restrict__ A,
                                                 const float* __restrict__ B,
                                                 float* __restrict__ C,
                                                 int M, int N, int K) {
  constexpr int BM = 16 * TM_;
  __shared__ float As[BK][BM + 4];
  __shared__ float Bs[BK][BN];
  int tid = threadIdx.x;
  int bm = blockIdx.y * BM;
  int bn = blockIdx.x * BN;
  int tx = tid & 15, ty = tid >> 4;
  float acc[TM_][TN] = {};
  for (int k0 = 0; k0 < K; k0 += BK) {
    #pragma unroll
    for (int it = 0; it < TM_ / 4; it++) {
      int f = tid + it * 256;
      int m = f >> 2;
      int k4 = f & 3;
      int gm = bm + m;
      float4 v = make_float4(0.f, 0.f, 0.f, 0.f);
      if (gm < M) v = *(const float4*)&A[(size_t)gm * K + k0 + k4 * 4];
      As[k4 * 4 + 0][m] = v.x;
      As[k4 * 4 + 1][m] = v.y;
      As[k4 * 4 + 2][m] = v.z;
      As[k4 * 4 + 3][m] = v.w;
    }
    {
      int kk = tid >> 4, n4 = tid & 15;
      *(float4*)&Bs[kk][n4 * 4] =
          *(const float4*)&B[(size_t)(k0 + kk) * N + bn + n4 * 4];
    }
    __syncthreads();
    #pragma unroll
    for (int kk = 0; kk < BK; kk++) {
      float a[TM_], b[TN];
      #pragma unroll
      for (int i = 0; i < TM_; i++) a[i] = As[kk][ty * TM_ + i];
      #pragma unroll
      for (int j = 0; j < TN; j++) b[j] = Bs[kk][tx * TN + j];
      #pragma unroll
      for (int i = 0; i < TM_; i++)
        #pragma unroll
        for (int j = 0; j < TN; j++) acc[i][j] += a[i] * b[j];
    }
    __syncthreads();
  }
  #pragma unroll
  for (int i = 0; i < TM_; i++) {
    int gm = bm + ty * TM_ + i;
    if (gm < M) {
      float4 v = make_float4(acc[i][0], acc[i][1], acc[i][2], acc[i][3]);
      *(float4*)&C[(size_t)gm * N + bn + tx * TN] = v;
    }
  }
}

// ---------------------------------------------------------------------------
// hg GEMM: hgT[h][m][c] (bf16, head-major) = A[M,256] @ Wg[256,1024]
// ---------------------------------------------------------------------------
__global__ __launch_bounds__(256) void gemm_hg_k(const float* __restrict__ A,
                                                 const float* __restrict__ B,
                                                 u16* __restrict__ hgT,
                                                 int M, int Nn) {
  constexpr int TM_ = 8;
  constexpr int BM = 128;
  const int N = NHEADS * HID;  // 1024
  const int K = HID;           // 256
  __shared__ float As[BK][BM + 4];
  __shared__ float Bs[BK][BN];
  int tid = threadIdx.x;
  int bm = blockIdx.y * BM;
  int bn = blockIdx.x * BN;
  int tx = tid & 15, ty = tid >> 4;
  float acc[TM_][TN] = {};
  for (int k0 = 0; k0 < K; k0 += BK) {
    #pragma unroll
    for (int it = 0; it < TM_ / 4; it++) {
      int f = tid + it * 256;
      int m = f >> 2;
      int k4 = f & 3;
      int gm = bm + m;
      float4 v = make_float4(0.f, 0.f, 0.f, 0.f);
      if (gm < M) v = *(const float4*)&A[(size_t)gm * K + k0 + k4 * 4];
      As[k4 * 4 + 0][m] = v.x;
      As[k4 * 4 + 1][m] = v.y;
      As[k4 * 4 + 2][m] = v.z;
      As[k4 * 4 + 3][m] = v.w;
    }
    {
      int kk = tid >> 4, n4 = tid & 15;
      *(float4*)&Bs[kk][n4 * 4] =
          *(const float4*)&B[(size_t)(k0 + kk) * N + bn + n4 * 4];
    }
    __syncthreads();
    #pragma unroll
    for (int kk = 0; kk < BK; kk++) {
      float a[TM_], b[TN];
      #pragma unroll
      for (int i = 0; i < TM_; i++) a[i] = As[kk][ty * TM_ + i];
      #pragma unroll
      for (int j = 0; j < TN; j++) b[j] = Bs[kk][tx * TN + j];
      #pragma unroll
      for (int i = 0; i < TM_; i++)
        #pragma unroll
        for (int j = 0; j < TN; j++) acc[i][j] += a[i] * b[j];
    }
    __syncthreads();
  }
  int gn = bn + tx * TN;
  int head = gn >> 8;
  int cc = gn & 255;
  #pragma unroll
  for (int i = 0; i < TM_; i++) {
    int gm = bm + ty * TM_ + i;
    if (gm < M) {
      ushort4 v;
      v.x = f2bf(acc[i][0]);
      v.y = f2bf(acc[i][1]);
      v.z = f2bf(acc[i][2]);
      v.w = f2bf(acc[i][3]);
      *(ushort4*)&hgT[((size_t)head * Nn + gm) * HID + cc] = v;
    }
  }
}

// ---------------------------------------------------------------------------
// GCN aggregation (vectorized): lane owns 4 channels (float4), 4 waves
// stride the edge list, LDS combine.  out = relu(agg + b)
// ---------------------------------------------------------------------------
__global__ __launch_bounds__(256) void gcn_agg_k(const float* __restrict__ t,
                                                 const int* __restrict__ row_ptr,
                                                 const int* __restrict__ csr_src,
                                                 const float* __restrict__ dinv,
                                                 const float* __restrict__ bias,
                                                 float* __restrict__ out) {
  int i = blockIdx.x;
  int tt = threadIdx.x;
  int q = tt >> 6, lane = tt & 63;
  int c4 = lane * 4;
  __shared__ float4 s_part[4][64];
  float di = dinv[i];
  int beg = row_ptr[i], end = row_ptr[i + 1];
  float4 acc = make_float4(0.f, 0.f, 0.f, 0.f);
  if (q == 0) {  // self loop
    float4 v = *(const float4*)&t[(size_t)i * HID + c4];
    float w = di * di;
    acc.x = v.x * w; acc.y = v.y * w; acc.z = v.z * w; acc.w = v.w * w;
  }
  for (int e = beg + q; e < end; e += 4) {
    int s = csr_src[e];
    float w = dinv[s] * di;
    float4 v = *(const float4*)&t[(size_t)s * HID + c4];
    acc.x += w * v.x; acc.y += w * v.y; acc.z += w * v.z; acc.w += w * v.w;
  }
  s_part[q][lane] = acc;
  __syncthreads();
  int c = tt;
  const float* f = (const float*)s_part;
  float a = (f[c] + f[256 + c]) + (f[512 + c] + f[768 + c]);
  out[(size_t)i * HID + c] = fmaxf(a + bias[c], 0.f);
}

// ---------------------------------------------------------------------------
// Attention weight projections: w_s[k][h] = <Wg[k, h*256:...], att_src[h]>
// one block per k, block-wide reduce per head.
// ---------------------------------------------------------------------------
__global__ __launch_bounds__(256) void watt_k(const float* __restrict__ Wg,
                                              const float* __restrict__ att_src,
                                              const float* __restrict__ att_dst,
                                              float* __restrict__ w_s,
                                              float* __restrict__ w_d) {
  int k = blockIdx.x;   // 0..255
  int c = threadIdx.x;  // 0..255
  int wv = c >> 6, ln = c & 63;
  __shared__ float red_s[4][NHEADS];
  __shared__ float red_d[4][NHEADS];
  #pragma unroll
  for (int h = 0; h < NHEADS; h++) {
    float w = Wg[(size_t)k * (NHEADS * HID) + h * HID + c];
    float vs = w * att_src[h * HID + c];
    float vd = w * att_dst[h * HID + c];
    #pragma unroll
    for (int off = 32; off; off >>= 1) {
      vs += __shfl_xor(vs, off);
      vd += __shfl_xor(vd, off);
    }
    if (ln == 0) { red_s[wv][h] = vs; red_d[wv][h] = vd; }
  }
  __syncthreads();
  if (c < NHEADS) {
    w_s[k * NHEADS + c] = red_s[0][c] + red_s[1][c] + red_s[2][c] + red_s[3][c];
    w_d[k * NHEADS + c] = red_d[0][c] + red_d[1][c] + red_d[2][c] + red_d[3][c];
  }
}

// ---------------------------------------------------------------------------
// a_src[n][h] = <h2[n,:], w_s[:,h]>   (8 nodes/block, 32 lanes/node)
// ---------------------------------------------------------------------------
__global__ __launch_bounds__(256) void att_proj_k(const float* __restrict__ h2,
                                                  const float* __restrict__ w_s,
                                                  const float* __restrict__ w_d,
                                                  float* __restrict__ a_src,
                                                  float* __restrict__ a_dst, int N) {
  __shared__ float lws[HID][5];   // padded: avoid 4-way bank conflict
  __shared__ float lwd[HID][5];
  int t = threadIdx.x;
  #pragma unroll
  for (int h = 0; h < NHEADS; h++) {
    lws[t][h] = w_s[t * NHEADS + h];
    lwd[t][h] = w_d[t * NHEADS + h];
  }
  __syncthreads();
  int nl = t >> 5, l = t & 31;
  int n = blockIdx.x * 8 + nl;
  if (n >= N) return;
  const float* row = h2 + (size_t)n * HID;
  float as[NHEADS] = {}, ad[NHEADS] = {};
  #pragma unroll
  for (int j = 0; j < 8; j++) {
    int k = l + 32 * j;
    float v = row[k];
    #pragma unroll
    for (int h = 0; h < NHEADS; h++) {
      as[h] += v * lws[k][h];
      ad[h] += v * lwd[k][h];
    }
  }
  #pragma unroll
  for (int off = 16; off; off >>= 1) {
    #pragma unroll
    for (int h = 0; h < NHEADS; h++) {
      as[h] += __shfl_xor(as[h], off, 32);
      ad[h] += __shfl_xor(ad[h], off, 32);
    }
  }
  if (l < NHEADS) a_src[n * NHEADS + l] = as[l];
  else if (l < 2 * NHEADS) a_dst[n * NHEADS + (l - NHEADS)] = ad[l - NHEADS];
}

__device__ __forceinline__ float lrelu02(float x) { return x > 0.f ? x : 0.2f * x; }

// ---------------------------------------------------------------------------
// GAT aggregation: wave h owns head h.  Fast path (deg<=63): one lane per
// edge, softmax entirely in registers (shuffle max/sum).  Gather: lane owns
// 4 channels (ushort4 bf16), alphas broadcast via wave-local LDS.  Heads
// combined once through LDS at the end.
// ---------------------------------------------------------------------------
__global__ __launch_bounds__(256) void gat_agg_k(const u16* __restrict__ hgT,
                                                 const int* __restrict__ row_ptr,
                                                 const int* __restrict__ csr_src,
                                                 const float* __restrict__ a_src,
                                                 const float* __restrict__ a_dst,
                                                 const float* __restrict__ bg,
                                                 float* __restrict__ out, int Nn) {
  int i = blockIdx.x;
  int t = threadIdx.x;
  int hw = t >> 6, lane = t & 63;
  __shared__ int s_src[NHEADS][64];
  __shared__ float s_al[NHEADS][64];
  __shared__ float s_acc[NHEADS][64][4];
  int beg = row_ptr[i], end = row_ptr[i + 1];
  int deg = end - beg;
  float adh = a_dst[i * NHEADS + hw];
  const u16* slab = hgT + (size_t)hw * Nn * HID;
  int c4 = lane * 4;
  float a0 = 0.f, a1 = 0.f, a2 = 0.f, a3 = 0.f;

  if (deg <= 63) {
    // lanes 0..deg-1 = edges, lane deg = self-loop
    int s = (lane < deg) ? csr_src[beg + lane] : i;
    bool valid = (lane <= deg);
    float logit = valid ? lrelu02(a_src[s * NHEADS + hw] + adh) : -INFINITY;
    float m = logit;
    #pragma unroll
    for (int off = 32; off; off >>= 1) m = fmaxf(m, __shfl_xor(m, off));
    float ex = valid ? expf(logit - m) : 0.f;
    float z = ex;
    #pragma unroll
    for (int off = 32; off; off >>= 1) z += __shfl_xor(z, off);
    float al = ex / (z + 1e-16f);
    s_src[hw][lane] = s;
    s_al[hw][lane] = al;
    // wave-synchronous: same wave wrote these, no barrier needed
    for (int e = 0; e <= deg; e++) {
      int se = s_src[hw][e];
      float ae = s_al[hw][e];
      ushort4 v = *(const ushort4*)&slab[(size_t)se * HID + c4];
      a0 += ae * bf2f(v.x);
      a1 += ae * bf2f(v.y);
      a2 += ae * bf2f(v.z);
      a3 += ae * bf2f(v.w);
    }
  } else {
    // generic chunked path (rare)
    float lself = lrelu02(a_src[i * NHEADS + hw] + adh);
    float m = lself;
    for (int e = beg + lane; e < end; e += 64)
      m = fmaxf(m, lrelu02(a_src[csr_src[e] * NHEADS + hw] + adh));
    #pragma unroll
    for (int off = 32; off; off >>= 1) m = fmaxf(m, __shfl_xor(m, off));
    float z = (lane == 0) ? expf(lself - m) : 0.f;
    for (int e = beg + lane; e < end; e += 64)
      z += expf(lrelu02(a_src[csr_src[e] * NHEADS + hw] + adh) - m);
    #pragma unroll
    for (int off = 32; off; off >>= 1) z += __shfl_xor(z, off);
    float iz = 1.f / (z + 1e-16f);
    // self loop
    {
      float ae = expf(lself - m) * iz;
      ushort4 v = *(const ushort4*)&slab[(size_t)i * HID + c4];
      a0 += ae * bf2f(v.x); a1 += ae * bf2f(v.y);
      a2 += ae * bf2f(v.z); a3 += ae * bf2f(v.w);
    }
    for (int base = beg; base < end; base += 64) {
      int mc = min(64, end - base);
      int s = (lane < mc) ? csr_src[base + lane] : 0;
      float al = (lane < mc)
                     ? expf(lrelu02(a_src[s * NHEADS + hw] + adh) - m) * iz
                     : 0.f;
      s_src[hw][lane] = s;
      s_al[hw][lane] = al;
      for (int e = 0; e < mc; e++) {
        int se = s_src[hw][e];
        float ae = s_al[hw][e];
        ushort4 v = *(const ushort4*)&slab[(size_t)se * HID + c4];
        a0 += ae * bf2f(v.x); a1 += ae * bf2f(v.y);
        a2 += ae * bf2f(v.z); a3 += ae * bf2f(v.w);
      }
    }
  }
  s_acc[hw][lane][0] = a0;
  s_acc[hw][lane][1] = a1;
  s_acc[hw][lane][2] = a2;
  s_acc[hw][lane][3] = a3;
  __syncthreads();
  int c = t;
  const float* f = (const float*)s_acc;
  float a = (f[c] + f[256 + c]) + (f[512 + c] + f[768 + c]);
  out[(size_t)i * HID + c] = fmaxf(a * 0.25f + bg[c], 0.f);
}

// ---------------------------------------------------------------------------
// Segmented global mean pool (batch sorted) + tiny head GEMM
// ---------------------------------------------------------------------------
#define POOL_CHUNK 50
__global__ __launch_bounds__(256) void pool_acc_k(const float* __restrict__ h3,
                                                  const int* __restrict__ batch,
                                                  float* __restrict__ pooled,
                                                  float* __restrict__ gcnt, int N) {
  int c = threadIdx.x;
  int i0 = blockIdx.x * POOL_CHUNK;
  int i1 = min(i0 + POOL_CHUNK, N);
  if (i0 >= N) return;
  float acc = 0.f;
  int cur = batch[i0];
  int cnt_local = 0;
  for (int i = i0; i < i1; i++) {
    int g = batch[i];
    if (g != cur) {
      atomicAdd(&pooled[cur * HID + c], acc);
      if (c == 0) atomicAdd(&gcnt[cur], (float)cnt_local);
      acc = 0.f;
      cnt_local = 0;
      cur = g;
    }
    acc += h3[(size_t)i * HID + c];
    cnt_local++;
  }
  atomicAdd(&pooled[cur * HID + c], acc);
  if (c == 0) atomicAdd(&gcnt[cur], (float)cnt_local);
}

__global__ __launch_bounds__(128) void head_k(const float* __restrict__ pooled,
                                              const float* __restrict__ gcnt,
                                              const float* __restrict__ W_heads,
                                              const float* __restrict__ b_heads,
                                              float* __restrict__ out) {
  int tid = threadIdx.x;
  if (tid >= NGRAPHS * 4) return;
  int g = tid >> 2, k = tid & 3;
  float invc = 1.f / fmaxf(gcnt[g], 1.f);
  float acc = 0.f;
  for (int c = 0; c < HID; c++) acc += pooled[g * HID + c] * W_heads[c * 4 + k];
  out[g * 4 + k] = acc * invc + b_heads[k];
}

// ---------------------------------------------------------------------------
extern "C" void kernel_launch(void* const* d_in, const int* in_sizes, int n_in,
                              void* d_out, int out_size, void* d_ws, size_t ws_size,
                              hipStream_t stream) {
  const float* x = (const float*)d_in[0];
  const int* ei = (const int*)d_in[1];
  const int* batch = (const int*)d_in[2];
  const float* W1 = (const float*)d_in[3];
  const float* b1 = (const float*)d_in[4];
  const float* W2 = (const float*)d_in[5];
  const float* b2 = (const float*)d_in[6];
  const float* Wg = (const float*)d_in[7];
  const float* att_src = (const float*)d_in[8];
  const float* att_dst = (const float*)d_in[9];
  const float* bg = (const float*)d_in[10];
  const float* W_heads = (const float*)d_in[11];
  const float* b_heads = (const float*)d_in[12];
  float* out = (float*)d_out;

  const int N = in_sizes[0] / IN_DIM;   // 10000
  const int E = in_sizes[1] / 2;        // 160000
  const int* src = ei;
  const int* dst = ei + E;

  // workspace layout (256B aligned)
  char* ws = (char*)d_ws;
  size_t off = 0;
  auto take = [&](size_t bytes) -> char* {
    char* p = ws + off;
    off = (off + bytes + 255) & ~(size_t)255;
    return p;
  };
  int* cnt      = (int*)take((size_t)N * 4);
  int* row_ptr  = (int*)take((size_t)(N + 1) * 4);
  int* cursor   = (int*)take((size_t)N * 4);
  int* csr_src  = (int*)take((size_t)E * 4);
  float* dinv   = (float*)take((size_t)N * 4);
  float* a_srcv = (float*)take((size_t)N * NHEADS * 4);
  float* a_dstv = (float*)take((size_t)N * NHEADS * 4);
  float* w_s    = (float*)take((size_t)HID * NHEADS * 4);
  float* w_d    = (float*)take((size_t)HID * NHEADS * 4);
  float* pooled = (float*)take((size_t)NGRAPHS * HID * 4 + NGRAPHS * 4);
  float* gcnt   = pooled + NGRAPHS * HID;
  float* t      = (float*)take((size_t)N * HID * 4);
  float* h1     = (float*)take((size_t)N * HID * 4);
  float* h2     = (float*)take((size_t)N * HID * 4);
  u16*   hgT    = (u16*)take((size_t)N * NHEADS * HID * 2);
  float* h3     = h1;  // alias: h1 dead after t2 = h1@W2

  hipMemsetAsync(cnt, 0, (size_t)N * 4, stream);
  hipMemsetAsync(cursor, 0, (size_t)N * 4, stream);
  hipMemsetAsync(pooled, 0, (size_t)NGRAPHS * HID * 4 + NGRAPHS * 4, stream);

  int eb = (E + 255) / 256;
  count_edges_k<<<eb, 256, 0, stream>>>(dst, cnt, E);
  scan_k<<<1, 1024, 0, stream>>>(cnt, row_ptr, dinv, N);
  fill_csr_k<<<eb, 256, 0, stream>>>(src, dst, row_ptr, cursor, csr_src, E);
  watt_k<<<HID, 256, 0, stream>>>(Wg, att_src, att_dst, w_s, w_d);

  int mg64 = (N + 63) / 64;
  int mg128 = (N + 127) / 128;
  // layer 1: t = x @ W1 ; h1 = relu(agg(t) + b1)
  gemm_nn_k<4><<<dim3(HID / BN, mg64), 256, 0, stream>>>(x, W1, t, N, HID, IN_DIM);
  gcn_agg_k<<<N, 256, 0, stream>>>(t, row_ptr, csr_src, dinv, b1, h1);
  // layer 2: t = h1 @ W2 ; h2 = relu(agg(t) + b2)
  gemm_nn_k<4><<<dim3(HID / BN, mg64), 256, 0, stream>>>(h1, W2, t, N, HID, HID);
  gcn_agg_k<<<N, 256, 0, stream>>>(t, row_ptr, csr_src, dinv, b2, h2);
  // GAT: hgT (bf16, head-major) = h2 @ Wg ; logits via projected weights
  gemm_hg_k<<<dim3(NHEADS * HID / BN, mg128), 256, 0, stream>>>(h2, Wg, hgT, N, N);
  att_proj_k<<<(N + 7) / 8, 256, 0, stream>>>(h2, w_s, w_d, a_srcv, a_dstv, N);
  gat_agg_k<<<N, 256, 0, stream>>>(hgT, row_ptr, csr_src, a_srcv, a_dstv, bg, h3, N);
  // pool + heads
  int pb = (N + POOL_CHUNK - 1) / POOL_CHUNK;
  pool_acc_k<<<pb, 256, 0, stream>>>(h3, batch, pooled, gcnt, N);
  head_k<<<1, 128, 0, stream>>>(pooled, gcnt, W_heads, b_heads, out);
}

// Round 5
// 251.708 us; speedup vs baseline: 1.5321x; 1.1581x over previous
//
#include <hip/hip_runtime.h>
#include <cmath>

// Problem constants (from reference)
#define IN_DIM 128
#define HID 256
#define NHEADS 4
#define NGRAPHS 32

typedef unsigned short u16;
typedef __attribute__((ext_vector_type(8))) short bfrag8;   // 8 bf16 (4 VGPRs)
typedef __attribute__((ext_vector_type(4))) float f32x4;    // MFMA acc

// bf16 helpers (RNE)
__device__ __forceinline__ u16 f2bf(float x) {
  unsigned u = __float_as_uint(x);
  unsigned r = (u + 0x7fffu + ((u >> 16) & 1u)) >> 16;
  return (u16)r;
}
__device__ __forceinline__ float bf2f(u16 v) {
  return __uint_as_float(((unsigned)v) << 16);
}

// ---------------------------------------------------------------------------
// CSR build: count incoming edges per dst, exclusive scan, fill src lists
// ---------------------------------------------------------------------------
__global__ __launch_bounds__(256) void count_edges_k(const int* __restrict__ dst,
                                                     int* __restrict__ cnt, int E) {
  int i = blockIdx.x * 256 + threadIdx.x;
  if (i < E) atomicAdd(&cnt[dst[i]], 1);
}

__global__ __launch_bounds__(1024) void scan_k(const int* __restrict__ cnt,
                                               int* __restrict__ row_ptr,
                                               float* __restrict__ dinv, int n) {
  __shared__ int sdata[1024];
  __shared__ int s_carry;
  if (threadIdx.x == 0) s_carry = 0;
  __syncthreads();
  int nchunks = (n + 1023) >> 10;
  for (int c = 0; c < nchunks; c++) {
    int i = (c << 10) + threadIdx.x;
    int v = (i < n) ? cnt[i] : 0;
    sdata[threadIdx.x] = v;
    __syncthreads();
    for (int off = 1; off < 1024; off <<= 1) {
      int t = (threadIdx.x >= off) ? sdata[threadIdx.x - off] : 0;
      __syncthreads();
      sdata[threadIdx.x] += t;
      __syncthreads();
    }
    int excl = sdata[threadIdx.x] - v;
    if (i < n) {
      row_ptr[i] = s_carry + excl;
      dinv[i] = rsqrtf((float)(v + 1));  // degree includes self-loop
    }
    __syncthreads();
    if (threadIdx.x == 0) s_carry += sdata[1023];
    __syncthreads();
  }
  if (threadIdx.x == 0) row_ptr[n] = s_carry;
}

__global__ __launch_bounds__(256) void fill_csr_k(const int* __restrict__ src,
                                                  const int* __restrict__ dst,
                                                  const int* __restrict__ row_ptr,
                                                  int* __restrict__ cursor,
                                                  int* __restrict__ csr_src, int E) {
  int i = blockIdx.x * 256 + threadIdx.x;
  if (i < E) {
    int d = dst[i];
    int p = atomicAdd(&cursor[d], 1);
    csr_src[row_ptr[d] + p] = src[i];
  }
}

// ---------------------------------------------------------------------------
// Operand packing into MFMA fragment order (16x16x32 bf16), split hi/lo.
// Packed layout (u16 units): [(frag*KT + kt)*1024 + hl*512 + lane*8 + j]
//   A element (m,k): frag=m>>4, kt=k>>5, lane=(m&15)+16*((k>>3)&3), j=k&7
//   B element (k,n): frag=n>>4, kt=k>>5, lane=(n&15)+16*((k>>3)&3), j=k&7
// ---------------------------------------------------------------------------
__global__ __launch_bounds__(256) void pack_a_k(const float* __restrict__ A,
                                                u16* __restrict__ Ap,
                                                int K, int KT, int nfrag) {
  int wid = blockIdx.x * 4 + (threadIdx.x >> 6);
  int lane = threadIdx.x & 63;
  if (wid >= nfrag * KT) return;
  int fm = wid / KT, kt = wid - fm * KT;
  int m = fm * 16 + (lane & 15);
  int kb = kt * 32 + (lane >> 4) * 8;
  const float* src = A + (size_t)m * K + kb;
  float4 v0 = *(const float4*)src;
  float4 v1 = *(const float4*)(src + 4);
  float vv[8] = {v0.x, v0.y, v0.z, v0.w, v1.x, v1.y, v1.z, v1.w};
  u16 hi[8], lo[8];
  #pragma unroll
  for (int j = 0; j < 8; j++) {
    u16 h = f2bf(vv[j]);
    hi[j] = h;
    lo[j] = f2bf(vv[j] - bf2f(h));
  }
  u16* dst = Ap + ((size_t)fm * KT + kt) * 1024 + lane * 8;
  *(ushort4*)(dst)       = make_ushort4(hi[0], hi[1], hi[2], hi[3]);
  *(ushort4*)(dst + 4)   = make_ushort4(hi[4], hi[5], hi[6], hi[7]);
  *(ushort4*)(dst + 512) = make_ushort4(lo[0], lo[1], lo[2], lo[3]);
  *(ushort4*)(dst + 516) = make_ushort4(lo[4], lo[5], lo[6], lo[7]);
}

__global__ __launch_bounds__(256) void pack_b_k(const float* __restrict__ B,
                                                u16* __restrict__ Bp,
                                                int N, int KT, int nfrag) {
  int wid = blockIdx.x * 4 + (threadIdx.x >> 6);
  int lane = threadIdx.x & 63;
  if (wid >= nfrag * KT) return;
  int fn = wid / KT, kt = wid - fn * KT;
  int n = fn * 16 + (lane & 15);
  int kb = kt * 32 + (lane >> 4) * 8;
  float vv[8];
  #pragma unroll
  for (int j = 0; j < 8; j++) vv[j] = B[(size_t)(kb + j) * N + n];
  u16 hi[8], lo[8];
  #pragma unroll
  for (int j = 0; j < 8; j++) {
    u16 h = f2bf(vv[j]);
    hi[j] = h;
    lo[j] = f2bf(vv[j] - bf2f(h));
  }
  u16* dst = Bp + ((size_t)fn * KT + kt) * 1024 + lane * 8;
  *(ushort4*)(dst)       = make_ushort4(hi[0], hi[1], hi[2], hi[3]);
  *(ushort4*)(dst + 4)   = make_ushort4(hi[4], hi[5], hi[6], hi[7]);
  *(ushort4*)(dst + 512) = make_ushort4(lo[0], lo[1], lo[2], lo[3]);
  *(ushort4*)(dst + 516) = make_ushort4(lo[4], lo[5], lo[6], lo[7]);
}

// ---------------------------------------------------------------------------
// Split-bf16 MFMA GEMM, operands pre-packed, no LDS / no barriers.
// Block = 4 waves (2x2); wave = 32x32 output (2x2 fragments of 16x16).
// Block tile = 64x64; grid = (N/64, ceil(M/64)).
// acc = a_hi*b_hi + a_hi*b_lo + a_lo*b_hi  (fp32 accumulate)
// ---------------------------------------------------------------------------
template <int KT, bool BF16OUT>
__global__ __launch_bounds__(256) void mfma_gemm_k(const u16* __restrict__ Ap,
                                                   const u16* __restrict__ Bp,
                                                   float* __restrict__ Cf,
                                                   u16* __restrict__ Cbf,
                                                   int M, int ldc, int Nn) {
  int tid = threadIdx.x;
  int w = tid >> 6, lane = tid & 63;
  int wm = w >> 1, wn = w & 1;
  int fm0 = blockIdx.y * 4 + wm * 2;
  int fn0 = blockIdx.x * 4 + wn * 2;
  f32x4 acc[2][2] = {};
  #pragma unroll
  for (int kt = 0; kt < KT; kt++) {
    bfrag8 a_hi[2], a_lo[2], b_hi[2], b_lo[2];
    #pragma unroll
    for (int f = 0; f < 2; f++) {
      const u16* pa = Ap + ((size_t)(fm0 + f) * KT + kt) * 1024 + lane * 8;
      a_hi[f] = *(const bfrag8*)pa;
      a_lo[f] = *(const bfrag8*)(pa + 512);
      const u16* pb = Bp + ((size_t)(fn0 + f) * KT + kt) * 1024 + lane * 8;
      b_hi[f] = *(const bfrag8*)pb;
      b_lo[f] = *(const bfrag8*)(pb + 512);
    }
    #pragma unroll
    for (int f = 0; f < 2; f++) {
      #pragma unroll
      for (int g = 0; g < 2; g++) {
        acc[f][g] = __builtin_amdgcn_mfma_f32_16x16x32_bf16(a_hi[f], b_hi[g], acc[f][g], 0, 0, 0);
        acc[f][g] = __builtin_amdgcn_mfma_f32_16x16x32_bf16(a_hi[f], b_lo[g], acc[f][g], 0, 0, 0);
        acc[f][g] = __builtin_amdgcn_mfma_f32_16x16x32_bf16(a_lo[f], b_hi[g], acc[f][g], 0, 0, 0);
      }
    }
  }
  // epilogue: D col = lane&15, row = (lane>>4)*4 + r
  int r0 = (lane >> 4) * 4;
  int cl = lane & 15;
  #pragma unroll
  for (int f = 0; f < 2; f++) {
    #pragma unroll
    for (int g = 0; g < 2; g++) {
      int col = (fn0 + g) * 16 + cl;
      #pragma unroll
      for (int r = 0; r < 4; r++) {
        int row = (fm0 + f) * 16 + r0 + r;
        if (row < M) {
          if constexpr (BF16OUT) {
            int head = col >> 8, cc = col & 255;
            Cbf[((size_t)head * Nn + row) * HID + cc] = f2bf(acc[f][g][r]);
          } else {
            Cf[(size_t)row * ldc + col] = acc[f][g][r];
          }
        }
      }
    }
  }
}

// ---------------------------------------------------------------------------
// GCN aggregation (vectorized): lane owns 4 channels (float4), 4 waves
// stride the edge list, LDS combine.  out = relu(agg + b), written fp32
// (optional) AND packed split-bf16 in MFMA fragment order (K=256 -> KT=8).
// ---------------------------------------------------------------------------
template <bool WRITE_F32>
__global__ __launch_bounds__(256) void gcn_agg_k(const float* __restrict__ t,
                                                 const int* __restrict__ row_ptr,
                                                 const int* __restrict__ csr_src,
                                                 const float* __restrict__ dinv,
                                                 const float* __restrict__ bias,
                                                 float* __restrict__ out,
                                                 u16* __restrict__ apack) {
  int i = blockIdx.x;
  int tt = threadIdx.x;
  int q = tt >> 6, lane = tt & 63;
  int c4 = lane * 4;
  __shared__ float4 s_part[4][64];
  float di = dinv[i];
  int beg = row_ptr[i], end = row_ptr[i + 1];
  float4 acc = make_float4(0.f, 0.f, 0.f, 0.f);
  if (q == 0) {  // self loop
    float4 v = *(const float4*)&t[(size_t)i * HID + c4];
    float w = di * di;
    acc.x = v.x * w; acc.y = v.y * w; acc.z = v.z * w; acc.w = v.w * w;
  }
  for (int e = beg + q; e < end; e += 4) {
    int s = csr_src[e];
    float w = dinv[s] * di;
    float4 v = *(const float4*)&t[(size_t)s * HID + c4];
    acc.x += w * v.x; acc.y += w * v.y; acc.z += w * v.z; acc.w += w * v.w;
  }
  s_part[q][lane] = acc;
  __syncthreads();
  int c = tt;
  const float* f = (const float*)s_part;
  float a = (f[c] + f[256 + c]) + (f[512 + c] + f[768 + c]);
  float v = fmaxf(a + bias[c], 0.f);
  if (WRITE_F32) out[(size_t)i * HID + c] = v;
  // pack (m=i, k=c) split-bf16, KT=8
  int fm = i >> 4, kt = c >> 5;
  int pl = (i & 15) + 16 * ((c >> 3) & 3);
  int j = c & 7;
  u16 h = f2bf(v);
  size_t base = ((size_t)fm * 8 + kt) * 1024 + pl * 8 + j;
  apack[base] = h;
  apack[base + 512] = f2bf(v - bf2f(h));
}

// ---------------------------------------------------------------------------
// Attention weight projections: w_s[k][h] = <Wg[k, h*256:...], att_src[h]>
// ---------------------------------------------------------------------------
__global__ __launch_bounds__(256) void watt_k(const float* __restrict__ Wg,
                                              const float* __restrict__ att_src,
                                              const float* __restrict__ att_dst,
                                              float* __restrict__ w_s,
                                              float* __restrict__ w_d) {
  int k = blockIdx.x;   // 0..255
  int c = threadIdx.x;  // 0..255
  int wv = c >> 6, ln = c & 63;
  __shared__ float red_s[4][NHEADS];
  __shared__ float red_d[4][NHEADS];
  #pragma unroll
  for (int h = 0; h < NHEADS; h++) {
    float w = Wg[(size_t)k * (NHEADS * HID) + h * HID + c];
    float vs = w * att_src[h * HID + c];
    float vd = w * att_dst[h * HID + c];
    #pragma unroll
    for (int off = 32; off; off >>= 1) {
      vs += __shfl_xor(vs, off);
      vd += __shfl_xor(vd, off);
    }
    if (ln == 0) { red_s[wv][h] = vs; red_d[wv][h] = vd; }
  }
  __syncthreads();
  if (c < NHEADS) {
    w_s[k * NHEADS + c] = red_s[0][c] + red_s[1][c] + red_s[2][c] + red_s[3][c];
    w_d[k * NHEADS + c] = red_d[0][c] + red_d[1][c] + red_d[2][c] + red_d[3][c];
  }
}

// ---------------------------------------------------------------------------
// a_src[n][h] = <h2[n,:], w_s[:,h]>   (8 nodes/block, 32 lanes/node)
// ---------------------------------------------------------------------------
__global__ __launch_bounds__(256) void att_proj_k(const float* __restrict__ h2,
                                                  const float* __restrict__ w_s,
                                                  const float* __restrict__ w_d,
                                                  float* __restrict__ a_src,
                                                  float* __restrict__ a_dst, int N) {
  __shared__ float lws[HID][5];
  __shared__ float lwd[HID][5];
  int t = threadIdx.x;
  #pragma unroll
  for (int h = 0; h < NHEADS; h++) {
    lws[t][h] = w_s[t * NHEADS + h];
    lwd[t][h] = w_d[t * NHEADS + h];
  }
  __syncthreads();
  int nl = t >> 5, l = t & 31;
  int n = blockIdx.x * 8 + nl;
  if (n >= N) return;
  const float* row = h2 + (size_t)n * HID;
  float as[NHEADS] = {}, ad[NHEADS] = {};
  #pragma unroll
  for (int j = 0; j < 8; j++) {
    int k = l + 32 * j;
    float v = row[k];
    #pragma unroll
    for (int h = 0; h < NHEADS; h++) {
      as[h] += v * lws[k][h];
      ad[h] += v * lwd[k][h];
    }
  }
  #pragma unroll
  for (int off = 16; off; off >>= 1) {
    #pragma unroll
    for (int h = 0; h < NHEADS; h++) {
      as[h] += __shfl_xor(as[h], off, 32);
      ad[h] += __shfl_xor(ad[h], off, 32);
    }
  }
  if (l < NHEADS) a_src[n * NHEADS + l] = as[l];
  else if (l < 2 * NHEADS) a_dst[n * NHEADS + (l - NHEADS)] = ad[l - NHEADS];
}

__device__ __forceinline__ float lrelu02(float x) { return x > 0.f ? x : 0.2f * x; }

// ---------------------------------------------------------------------------
// GAT aggregation: wave h owns head h (softmax in registers for deg<=63),
// gather lane owns 4 channels (ushort4 bf16), heads combined via LDS.
// ---------------------------------------------------------------------------
__global__ __launch_bounds__(256) void gat_agg_k(const u16* __restrict__ hgT,
                                                 const int* __restrict__ row_ptr,
                                                 const int* __restrict__ csr_src,
                                                 const float* __restrict__ a_src,
                                                 const float* __restrict__ a_dst,
                                                 const float* __restrict__ bg,
                                                 float* __restrict__ out, int Nn) {
  int i = blockIdx.x;
  int t = threadIdx.x;
  int hw = t >> 6, lane = t & 63;
  __shared__ int s_src[NHEADS][64];
  __shared__ float s_al[NHEADS][64];
  __shared__ float s_acc[NHEADS][64][4];
  int beg = row_ptr[i], end = row_ptr[i + 1];
  int deg = end - beg;
  float adh = a_dst[i * NHEADS + hw];
  const u16* slab = hgT + (size_t)hw * Nn * HID;
  int c4 = lane * 4;
  float a0 = 0.f, a1 = 0.f, a2 = 0.f, a3 = 0.f;

  if (deg <= 63) {
    int s = (lane < deg) ? csr_src[beg + lane] : i;
    bool valid = (lane <= deg);
    float logit = valid ? lrelu02(a_src[s * NHEADS + hw] + adh) : -INFINITY;
    float m = logit;
    #pragma unroll
    for (int off = 32; off; off >>= 1) m = fmaxf(m, __shfl_xor(m, off));
    float ex = valid ? expf(logit - m) : 0.f;
    float z = ex;
    #pragma unroll
    for (int off = 32; off; off >>= 1) z += __shfl_xor(z, off);
    float al = ex / (z + 1e-16f);
    s_src[hw][lane] = s;
    s_al[hw][lane] = al;
    for (int e = 0; e <= deg; e++) {
      int se = s_src[hw][e];
      float ae = s_al[hw][e];
      ushort4 v = *(const ushort4*)&slab[(size_t)se * HID + c4];
      a0 += ae * bf2f(v.x);
      a1 += ae * bf2f(v.y);
      a2 += ae * bf2f(v.z);
      a3 += ae * bf2f(v.w);
    }
  } else {
    float lself = lrelu02(a_src[i * NHEADS + hw] + adh);
    float m = lself;
    for (int e = beg + lane; e < end; e += 64)
      m = fmaxf(m, lrelu02(a_src[csr_src[e] * NHEADS + hw] + adh));
    #pragma unroll
    for (int off = 32; off; off >>= 1) m = fmaxf(m, __shfl_xor(m, off));
    float z = (lane == 0) ? expf(lself - m) : 0.f;
    for (int e = beg + lane; e < end; e += 64)
      z += expf(lrelu02(a_src[csr_src[e] * NHEADS + hw] + adh) - m);
    #pragma unroll
    for (int off = 32; off; off >>= 1) z += __shfl_xor(z, off);
    float iz = 1.f / (z + 1e-16f);
    {
      float ae = expf(lself - m) * iz;
      ushort4 v = *(const ushort4*)&slab[(size_t)i * HID + c4];
      a0 += ae * bf2f(v.x); a1 += ae * bf2f(v.y);
      a2 += ae * bf2f(v.z); a3 += ae * bf2f(v.w);
    }
    for (int base = beg; base < end; base += 64) {
      int mc = min(64, end - base);
      int s = (lane < mc) ? csr_src[base + lane] : 0;
      float al = (lane < mc)
                     ? expf(lrelu02(a_src[s * NHEADS + hw] + adh) - m) * iz
                     : 0.f;
      s_src[hw][lane] = s;
      s_al[hw][lane] = al;
      for (int e = 0; e < mc; e++) {
        int se = s_src[hw][e];
        float ae = s_al[hw][e];
        ushort4 v = *(const ushort4*)&slab[(size_t)se * HID + c4];
        a0 += ae * bf2f(v.x); a1 += ae * bf2f(v.y);
        a2 += ae * bf2f(v.z); a3 += ae * bf2f(v.w);
      }
    }
  }
  s_acc[hw][lane][0] = a0;
  s_acc[hw][lane][1] = a1;
  s_acc[hw][lane][2] = a2;
  s_acc[hw][lane][3] = a3;
  __syncthreads();
  int c = t;
  const float* f = (const float*)s_acc;
  float a = (f[c] + f[256 + c]) + (f[512 + c] + f[768 + c]);
  out[(size_t)i * HID + c] = fmaxf(a * 0.25f + bg[c], 0.f);
}

// ---------------------------------------------------------------------------
// Segmented global mean pool (batch sorted) + tiny head GEMM
// ---------------------------------------------------------------------------
#define POOL_CHUNK 50
__global__ __launch_bounds__(256) void pool_acc_k(const float* __restrict__ h3,
                                                  const int* __restrict__ batch,
                                                  float* __restrict__ pooled,
                                                  float* __restrict__ gcnt, int N) {
  int c = threadIdx.x;
  int i0 = blockIdx.x * POOL_CHUNK;
  int i1 = min(i0 + POOL_CHUNK, N);
  if (i0 >= N) return;
  float acc = 0.f;
  int cur = batch[i0];
  int cnt_local = 0;
  for (int i = i0; i < i1; i++) {
    int g = batch[i];
    if (g != cur) {
      atomicAdd(&pooled[cur * HID + c], acc);
      if (c == 0) atomicAdd(&gcnt[cur], (float)cnt_local);
      acc = 0.f;
      cnt_local = 0;
      cur = g;
    }
    acc += h3[(size_t)i * HID + c];
    cnt_local++;
  }
  atomicAdd(&pooled[cur * HID + c], acc);
  if (c == 0) atomicAdd(&gcnt[cur], (float)cnt_local);
}

__global__ __launch_bounds__(128) void head_k(const float* __restrict__ pooled,
                                              const float* __restrict__ gcnt,
                                              const float* __restrict__ W_heads,
                                              const float* __restrict__ b_heads,
                                              float* __restrict__ out) {
  int tid = threadIdx.x;
  if (tid >= NGRAPHS * 4) return;
  int g = tid >> 2, k = tid & 3;
  float invc = 1.f / fmaxf(gcnt[g], 1.f);
  float acc = 0.f;
  for (int c = 0; c < HID; c++) acc += pooled[g * HID + c] * W_heads[c * 4 + k];
  out[g * 4 + k] = acc * invc + b_heads[k];
}

// ---------------------------------------------------------------------------
extern "C" void kernel_launch(void* const* d_in, const int* in_sizes, int n_in,
                              void* d_out, int out_size, void* d_ws, size_t ws_size,
                              hipStream_t stream) {
  const float* x = (const float*)d_in[0];
  const int* ei = (const int*)d_in[1];
  const int* batch = (const int*)d_in[2];
  const float* W1 = (const float*)d_in[3];
  const float* b1 = (const float*)d_in[4];
  const float* W2 = (const float*)d_in[5];
  const float* b2 = (const float*)d_in[6];
  const float* Wg = (const float*)d_in[7];
  const float* att_src = (const float*)d_in[8];
  const float* att_dst = (const float*)d_in[9];
  const float* bg = (const float*)d_in[10];
  const float* W_heads = (const float*)d_in[11];
  const float* b_heads = (const float*)d_in[12];
  float* out = (float*)d_out;

  const int N = in_sizes[0] / IN_DIM;   // 10000
  const int E = in_sizes[1] / 2;        // 160000
  const int* src = ei;
  const int* dst = ei + E;

  const int NFM = N / 16;               // 625 A-row fragments (N % 16 == 0)
  const int NFMP = ((N + 63) / 64) * 4; // padded to block multiple (628)

  // workspace layout (256B aligned)
  char* ws = (char*)d_ws;
  size_t off = 0;
  auto take = [&](size_t bytes) -> char* {
    char* p = ws + off;
    off = (off + bytes + 255) & ~(size_t)255;
    return p;
  };
  int* cnt      = (int*)take((size_t)N * 4);
  int* row_ptr  = (int*)take((size_t)(N + 1) * 4);
  int* cursor   = (int*)take((size_t)N * 4);
  int* csr_src  = (int*)take((size_t)E * 4);
  float* dinv   = (float*)take((size_t)N * 4);
  float* a_srcv = (float*)take((size_t)N * NHEADS * 4);
  float* a_dstv = (float*)take((size_t)N * NHEADS * 4);
  float* w_s    = (float*)take((size_t)HID * NHEADS * 4);
  float* w_d    = (float*)take((size_t)HID * NHEADS * 4);
  float* pooled = (float*)take((size_t)NGRAPHS * HID * 4 + NGRAPHS * 4);
  float* gcnt   = pooled + NGRAPHS * HID;
  float* t      = (float*)take((size_t)N * HID * 4);
  float* h1     = (float*)take((size_t)N * HID * 4);
  float* h2     = (float*)take((size_t)N * HID * 4);
  u16*   hgT    = (u16*)take((size_t)N * NHEADS * HID * 2);
  // packed operands (u16): frag stride = KT*1024 u16
  u16*   xp     = (u16*)take((size_t)NFMP * 4 * 1024 * 2);   // K=128, KT=4
  u16*   h1p    = (u16*)take((size_t)NFMP * 8 * 1024 * 2);   // K=256, KT=8
  u16*   h2p    = (u16*)take((size_t)NFMP * 8 * 1024 * 2);
  u16*   w1p    = (u16*)take((size_t)16 * 4 * 1024 * 2);     // N=256 -> 16 frags
  u16*   w2p    = (u16*)take((size_t)16 * 8 * 1024 * 2);
  u16*   wgp    = (u16*)take((size_t)64 * 8 * 1024 * 2);     // N=1024 -> 64 frags
  float* h3     = h1;  // alias: h1 fp32 unused (packed path), reused for h3

  hipMemsetAsync(cnt, 0, (size_t)N * 4, stream);
  hipMemsetAsync(cursor, 0, (size_t)N * 4, stream);
  hipMemsetAsync(pooled, 0, (size_t)NGRAPHS * HID * 4 + NGRAPHS * 4, stream);

  int eb = (E + 255) / 256;
  count_edges_k<<<eb, 256, 0, stream>>>(dst, cnt, E);
  scan_k<<<1, 1024, 0, stream>>>(cnt, row_ptr, dinv, N);
  fill_csr_k<<<eb, 256, 0, stream>>>(src, dst, row_ptr, cursor, csr_src, E);
  watt_k<<<HID, 256, 0, stream>>>(Wg, att_src, att_dst, w_s, w_d);

  // pack inputs/weights
  pack_a_k<<<(NFM * 4 + 3) / 4, 256, 0, stream>>>(x, xp, IN_DIM, 4, NFM);
  pack_b_k<<<(16 * 4 + 3) / 4, 256, 0, stream>>>(W1, w1p, HID, 4, 16);
  pack_b_k<<<(16 * 8 + 3) / 4, 256, 0, stream>>>(W2, w2p, HID, 8, 16);
  pack_b_k<<<(64 * 8 + 3) / 4, 256, 0, stream>>>(Wg, wgp, NHEADS * HID, 8, 64);

  int mg64 = (N + 63) / 64;
  // layer 1: t = x @ W1 ; h1p = pack(relu(agg(t) + b1))
  mfma_gemm_k<4, false><<<dim3(4, mg64), 256, 0, stream>>>(xp, w1p, t, nullptr, N, HID, N);
  gcn_agg_k<false><<<N, 256, 0, stream>>>(t, row_ptr, csr_src, dinv, b1, h1, h1p);
  // layer 2: t = h1 @ W2 ; h2 (fp32 + packed) = relu(agg(t) + b2)
  mfma_gemm_k<8, false><<<dim3(4, mg64), 256, 0, stream>>>(h1p, w2p, t, nullptr, N, HID, N);
  gcn_agg_k<true><<<N, 256, 0, stream>>>(t, row_ptr, csr_src, dinv, b2, h2, h2p);
  // GAT: hgT (bf16 head-major) = h2 @ Wg ; logits via projected weights
  mfma_gemm_k<8, true><<<dim3(16, mg64), 256, 0, stream>>>(h2p, wgp, nullptr, hgT, N, 0, N);
  att_proj_k<<<(N + 7) / 8, 256, 0, stream>>>(h2, w_s, w_d, a_srcv, a_dstv, N);
  gat_agg_k<<<N, 256, 0, stream>>>(hgT, row_ptr, csr_src, a_srcv, a_dstv, bg, h3, N);
  // pool + heads
  int pb = (N + POOL_CHUNK - 1) / POOL_CHUNK;
  pool_acc_k<<<pb, 256, 0, stream>>>(h3, batch, pooled, gcnt, N);
  head_k<<<1, 128, 0, stream>>>(pooled, gcnt, W_heads, b_heads, out);
}

// Round 6
// 232.473 us; speedup vs baseline: 1.6588x; 1.0827x over previous
//
#include <hip/hip_runtime.h>
#include <cmath>

// Problem constants (from reference)
#define IN_DIM 128
#define HID 256
#define NHEADS 4
#define NGRAPHS 32

typedef unsigned short u16;
typedef __attribute__((ext_vector_type(8))) short bfrag8;   // 8 bf16 (4 VGPRs)
typedef __attribute__((ext_vector_type(4))) float f32x4;    // MFMA acc

// bf16 helpers (RNE)
__device__ __forceinline__ u16 f2bf(float x) {
  unsigned u = __float_as_uint(x);
  unsigned r = (u + 0x7fffu + ((u >> 16) & 1u)) >> 16;
  return (u16)r;
}
__device__ __forceinline__ float bf2f(u16 v) {
  return __uint_as_float(((unsigned)v) << 16);
}

// ---------------------------------------------------------------------------
// CSR build: count incoming edges per dst, exclusive scan, fill src lists
// ---------------------------------------------------------------------------
__global__ __launch_bounds__(256) void count_edges_k(const int* __restrict__ dst,
                                                     int* __restrict__ cnt, int E) {
  int i = blockIdx.x * 256 + threadIdx.x;
  if (i < E) atomicAdd(&cnt[dst[i]], 1);
}

__global__ __launch_bounds__(1024) void scan_k(const int* __restrict__ cnt,
                                               int* __restrict__ row_ptr,
                                               float* __restrict__ dinv, int n) {
  __shared__ int sdata[1024];
  __shared__ int s_carry;
  if (threadIdx.x == 0) s_carry = 0;
  __syncthreads();
  int nchunks = (n + 1023) >> 10;
  for (int c = 0; c < nchunks; c++) {
    int i = (c << 10) + threadIdx.x;
    int v = (i < n) ? cnt[i] : 0;
    sdata[threadIdx.x] = v;
    __syncthreads();
    for (int off = 1; off < 1024; off <<= 1) {
      int t = (threadIdx.x >= off) ? sdata[threadIdx.x - off] : 0;
      __syncthreads();
      sdata[threadIdx.x] += t;
      __syncthreads();
    }
    int excl = sdata[threadIdx.x] - v;
    if (i < n) {
      row_ptr[i] = s_carry + excl;
      dinv[i] = rsqrtf((float)(v + 1));  // degree includes self-loop
    }
    __syncthreads();
    if (threadIdx.x == 0) s_carry += sdata[1023];
    __syncthreads();
  }
  if (threadIdx.x == 0) row_ptr[n] = s_carry;
}

__global__ __launch_bounds__(256) void fill_csr_k(const int* __restrict__ src,
                                                  const int* __restrict__ dst,
                                                  const int* __restrict__ row_ptr,
                                                  int* __restrict__ cursor,
                                                  int* __restrict__ csr_src, int E) {
  int i = blockIdx.x * 256 + threadIdx.x;
  if (i < E) {
    int d = dst[i];
    int p = atomicAdd(&cursor[d], 1);
    csr_src[row_ptr[d] + p] = src[i];
  }
}

// ---------------------------------------------------------------------------
// Operand packing into MFMA fragment order (16x16x32 bf16), split hi/lo.
// Packed layout (u16 units): [(frag*KT + kt)*1024 + hl*512 + lane*8 + j]
//   A element (m,k): frag=m>>4, kt=k>>5, lane=(m&15)+16*((k>>3)&3), j=k&7
//   B element (k,n): frag=n>>4, kt=k>>5, lane=(n&15)+16*((k>>3)&3), j=k&7
// ---------------------------------------------------------------------------
__global__ __launch_bounds__(256) void pack_a_k(const float* __restrict__ A,
                                                u16* __restrict__ Ap,
                                                int K, int KT, int nfrag) {
  int wid = blockIdx.x * 4 + (threadIdx.x >> 6);
  int lane = threadIdx.x & 63;
  if (wid >= nfrag * KT) return;
  int fm = wid / KT, kt = wid - fm * KT;
  int m = fm * 16 + (lane & 15);
  int kb = kt * 32 + (lane >> 4) * 8;
  const float* src = A + (size_t)m * K + kb;
  float4 v0 = *(const float4*)src;
  float4 v1 = *(const float4*)(src + 4);
  float vv[8] = {v0.x, v0.y, v0.z, v0.w, v1.x, v1.y, v1.z, v1.w};
  u16 hi[8], lo[8];
  #pragma unroll
  for (int j = 0; j < 8; j++) {
    u16 h = f2bf(vv[j]);
    hi[j] = h;
    lo[j] = f2bf(vv[j] - bf2f(h));
  }
  u16* dst = Ap + ((size_t)fm * KT + kt) * 1024 + lane * 8;
  *(ushort4*)(dst)       = make_ushort4(hi[0], hi[1], hi[2], hi[3]);
  *(ushort4*)(dst + 4)   = make_ushort4(hi[4], hi[5], hi[6], hi[7]);
  *(ushort4*)(dst + 512) = make_ushort4(lo[0], lo[1], lo[2], lo[3]);
  *(ushort4*)(dst + 516) = make_ushort4(lo[4], lo[5], lo[6], lo[7]);
}

__global__ __launch_bounds__(256) void pack_b_k(const float* __restrict__ B,
                                                u16* __restrict__ Bp,
                                                int N, int KT, int nfrag) {
  int wid = blockIdx.x * 4 + (threadIdx.x >> 6);
  int lane = threadIdx.x & 63;
  if (wid >= nfrag * KT) return;
  int fn = wid / KT, kt = wid - fn * KT;
  int n = fn * 16 + (lane & 15);
  int kb = kt * 32 + (lane >> 4) * 8;
  float vv[8];
  #pragma unroll
  for (int j = 0; j < 8; j++) vv[j] = B[(size_t)(kb + j) * N + n];
  u16 hi[8], lo[8];
  #pragma unroll
  for (int j = 0; j < 8; j++) {
    u16 h = f2bf(vv[j]);
    hi[j] = h;
    lo[j] = f2bf(vv[j] - bf2f(h));
  }
  u16* dst = Bp + ((size_t)fn * KT + kt) * 1024 + lane * 8;
  *(ushort4*)(dst)       = make_ushort4(hi[0], hi[1], hi[2], hi[3]);
  *(ushort4*)(dst + 4)   = make_ushort4(hi[4], hi[5], hi[6], hi[7]);
  *(ushort4*)(dst + 512) = make_ushort4(lo[0], lo[1], lo[2], lo[3]);
  *(ushort4*)(dst + 516) = make_ushort4(lo[4], lo[5], lo[6], lo[7]);
}

// ---------------------------------------------------------------------------
// Split-bf16 MFMA GEMM, operands pre-packed, no LDS / no barriers.
// Block = 4 waves (2x2); wave = 32x32 output; block tile 64x64.
// ALO=true: acc = a_hi*b_hi + a_hi*b_lo + a_lo*b_hi  (~fp32 precision)
// ALO=false: 2-term, A-hi only (saves A-lo fetch; ~bf16-input precision)
// OMODE 0: bf16 row-major C [M][HID];  OMODE 1: bf16 head-major hgT
// ---------------------------------------------------------------------------
template <int KT, int OMODE, bool ALO>
__global__ __launch_bounds__(256) void mfma_gemm_k(const u16* __restrict__ Ap,
                                                   const u16* __restrict__ Bp,
                                                   u16* __restrict__ Cb,
                                                   int M, int Nn) {
  int tid = threadIdx.x;
  int w = tid >> 6, lane = tid & 63;
  int wm = w >> 1, wn = w & 1;
  int fm0 = blockIdx.y * 4 + wm * 2;
  int fn0 = blockIdx.x * 4 + wn * 2;
  f32x4 acc[2][2] = {};
  #pragma unroll
  for (int kt = 0; kt < KT; kt++) {
    bfrag8 a_hi[2], a_lo[2], b_hi[2], b_lo[2];
    #pragma unroll
    for (int f = 0; f < 2; f++) {
      const u16* pa = Ap + ((size_t)(fm0 + f) * KT + kt) * 1024 + lane * 8;
      a_hi[f] = *(const bfrag8*)pa;
      if constexpr (ALO) a_lo[f] = *(const bfrag8*)(pa + 512);
      const u16* pb = Bp + ((size_t)(fn0 + f) * KT + kt) * 1024 + lane * 8;
      b_hi[f] = *(const bfrag8*)pb;
      b_lo[f] = *(const bfrag8*)(pb + 512);
    }
    #pragma unroll
    for (int f = 0; f < 2; f++) {
      #pragma unroll
      for (int g = 0; g < 2; g++) {
        acc[f][g] = __builtin_amdgcn_mfma_f32_16x16x32_bf16(a_hi[f], b_hi[g], acc[f][g], 0, 0, 0);
        acc[f][g] = __builtin_amdgcn_mfma_f32_16x16x32_bf16(a_hi[f], b_lo[g], acc[f][g], 0, 0, 0);
        if constexpr (ALO)
          acc[f][g] = __builtin_amdgcn_mfma_f32_16x16x32_bf16(a_lo[f], b_hi[g], acc[f][g], 0, 0, 0);
      }
    }
  }
  // epilogue: D col = lane&15, row = (lane>>4)*4 + r
  int r0 = (lane >> 4) * 4;
  int cl = lane & 15;
  #pragma unroll
  for (int f = 0; f < 2; f++) {
    #pragma unroll
    for (int g = 0; g < 2; g++) {
      int col = (fn0 + g) * 16 + cl;
      #pragma unroll
      for (int r = 0; r < 4; r++) {
        int row = (fm0 + f) * 16 + r0 + r;
        if (row < M) {
          if constexpr (OMODE == 1) {
            int head = col >> 8, cc = col & 255;
            Cb[((size_t)head * Nn + row) * HID + cc] = f2bf(acc[f][g][r]);
          } else {
            Cb[(size_t)row * HID + col] = f2bf(acc[f][g][r]);
          }
        }
      }
    }
  }
}

// ---------------------------------------------------------------------------
// GCN aggregation from bf16 t: lane owns 4 channels (ushort4), 4 waves
// stride edges (2-unrolled).  v = relu(agg + b); packed split-bf16 out.
// LOGITS: also computes a_src/a_dst = <v_row, w_s/w_d> fused (layer 2).
// ---------------------------------------------------------------------------
template <bool LOGITS, bool PACK_LO>
__global__ __launch_bounds__(256) void gcn_agg_k(const u16* __restrict__ t,
                                                 const int* __restrict__ row_ptr,
                                                 const int* __restrict__ csr_src,
                                                 const float* __restrict__ dinv,
                                                 const float* __restrict__ bias,
                                                 u16* __restrict__ apack,
                                                 const float* __restrict__ w_s,
                                                 const float* __restrict__ w_d,
                                                 float* __restrict__ a_src,
                                                 float* __restrict__ a_dst) {
  int i = blockIdx.x;
  int tt = threadIdx.x;
  int q = tt >> 6, lane = tt & 63;
  int c4 = lane * 4;
  __shared__ float4 s_part[4][64];
  float di = dinv[i];
  int beg = row_ptr[i], end = row_ptr[i + 1];
  float4 acc = make_float4(0.f, 0.f, 0.f, 0.f);
  if (q == 0) {  // self loop
    ushort4 u = *(const ushort4*)&t[(size_t)i * HID + c4];
    float w = di * di;
    acc.x = w * bf2f(u.x); acc.y = w * bf2f(u.y);
    acc.z = w * bf2f(u.z); acc.w = w * bf2f(u.w);
  }
  int e = beg + q;
  for (; e + 4 < end; e += 8) {
    int s0 = csr_src[e], s1 = csr_src[e + 4];
    float w0 = dinv[s0] * di, w1 = dinv[s1] * di;
    ushort4 u0 = *(const ushort4*)&t[(size_t)s0 * HID + c4];
    ushort4 u1 = *(const ushort4*)&t[(size_t)s1 * HID + c4];
    acc.x += w0 * bf2f(u0.x) + w1 * bf2f(u1.x);
    acc.y += w0 * bf2f(u0.y) + w1 * bf2f(u1.y);
    acc.z += w0 * bf2f(u0.z) + w1 * bf2f(u1.z);
    acc.w += w0 * bf2f(u0.w) + w1 * bf2f(u1.w);
  }
  if (e < end) {
    int s = csr_src[e];
    float w = dinv[s] * di;
    ushort4 u = *(const ushort4*)&t[(size_t)s * HID + c4];
    acc.x += w * bf2f(u.x); acc.y += w * bf2f(u.y);
    acc.z += w * bf2f(u.z); acc.w += w * bf2f(u.w);
  }
  s_part[q][lane] = acc;
  __syncthreads();
  int c = tt;
  const float* f = (const float*)s_part;
  float a = (f[c] + f[256 + c]) + (f[512 + c] + f[768 + c]);
  float v = fmaxf(a + bias[c], 0.f);
  // pack (m=i, k=c) split-bf16, KT=8
  {
    int fm = i >> 4, kt = c >> 5;
    int pl = (i & 15) + 16 * ((c >> 3) & 3);
    int j = c & 7;
    u16 h = f2bf(v);
    size_t base = ((size_t)fm * 8 + kt) * 1024 + pl * 8 + j;
    apack[base] = h;
    if constexpr (PACK_LO) apack[base + 512] = f2bf(v - bf2f(h));
  }
  if constexpr (LOGITS) {
    __shared__ float s_rs[4][NHEADS];
    __shared__ float s_rd[4][NHEADS];
    float4 wsv = *(const float4*)&w_s[c * NHEADS];
    float4 wdv = *(const float4*)&w_d[c * NHEADS];
    float ps[NHEADS] = {v * wsv.x, v * wsv.y, v * wsv.z, v * wsv.w};
    float pd[NHEADS] = {v * wdv.x, v * wdv.y, v * wdv.z, v * wdv.w};
    #pragma unroll
    for (int off = 32; off; off >>= 1) {
      #pragma unroll
      for (int h = 0; h < NHEADS; h++) {
        ps[h] += __shfl_xor(ps[h], off);
        pd[h] += __shfl_xor(pd[h], off);
      }
    }
    int wv = q;
    if (lane == 0) {
      #pragma unroll
      for (int h = 0; h < NHEADS; h++) { s_rs[wv][h] = ps[h]; s_rd[wv][h] = pd[h]; }
    }
    __syncthreads();
    if (tt < NHEADS)
      a_src[i * NHEADS + tt] = s_rs[0][tt] + s_rs[1][tt] + s_rs[2][tt] + s_rs[3][tt];
    else if (tt < 2 * NHEADS) {
      int h = tt - NHEADS;
      a_dst[i * NHEADS + h] = s_rd[0][h] + s_rd[1][h] + s_rd[2][h] + s_rd[3][h];
    }
  }
}

// ---------------------------------------------------------------------------
// Attention weight projections: w_s[k][h] = <Wg[k, h*256:...], att_src[h]>
// ---------------------------------------------------------------------------
__global__ __launch_bounds__(256) void watt_k(const float* __restrict__ Wg,
                                              const float* __restrict__ att_src,
                                              const float* __restrict__ att_dst,
                                              float* __restrict__ w_s,
                                              float* __restrict__ w_d) {
  int k = blockIdx.x;   // 0..255
  int c = threadIdx.x;  // 0..255
  int wv = c >> 6, ln = c & 63;
  __shared__ float red_s[4][NHEADS];
  __shared__ float red_d[4][NHEADS];
  #pragma unroll
  for (int h = 0; h < NHEADS; h++) {
    float w = Wg[(size_t)k * (NHEADS * HID) + h * HID + c];
    float vs = w * att_src[h * HID + c];
    float vd = w * att_dst[h * HID + c];
    #pragma unroll
    for (int off = 32; off; off >>= 1) {
      vs += __shfl_xor(vs, off);
      vd += __shfl_xor(vd, off);
    }
    if (ln == 0) { red_s[wv][h] = vs; red_d[wv][h] = vd; }
  }
  __syncthreads();
  if (c < NHEADS) {
    w_s[k * NHEADS + c] = red_s[0][c] + red_s[1][c] + red_s[2][c] + red_s[3][c];
    w_d[k * NHEADS + c] = red_d[0][c] + red_d[1][c] + red_d[2][c] + red_d[3][c];
  }
}

__device__ __forceinline__ float lrelu02(float x) { return x > 0.f ? x : 0.2f * x; }

// ---------------------------------------------------------------------------
// GAT aggregation: wave h owns head h (softmax in registers for deg<=63),
// gather lane owns 4 channels (ushort4 bf16), 4x-unrolled; LDS head combine.
// ---------------------------------------------------------------------------
__global__ __launch_bounds__(256) void gat_agg_k(const u16* __restrict__ hgT,
                                                 const int* __restrict__ row_ptr,
                                                 const int* __restrict__ csr_src,
                                                 const float* __restrict__ a_src,
                                                 const float* __restrict__ a_dst,
                                                 const float* __restrict__ bg,
                                                 float* __restrict__ out, int Nn) {
  int i = blockIdx.x;
  int t = threadIdx.x;
  int hw = t >> 6, lane = t & 63;
  __shared__ int s_src[NHEADS][64];
  __shared__ float s_al[NHEADS][64];
  __shared__ float s_acc[NHEADS][64][4];
  int beg = row_ptr[i], end = row_ptr[i + 1];
  int deg = end - beg;
  float adh = a_dst[i * NHEADS + hw];
  const u16* slab = hgT + (size_t)hw * Nn * HID;
  int c4 = lane * 4;
  float a0 = 0.f, a1 = 0.f, a2 = 0.f, a3 = 0.f;

  if (deg <= 63) {
    int s = (lane < deg) ? csr_src[beg + lane] : i;
    bool valid = (lane <= deg);
    float logit = valid ? lrelu02(a_src[s * NHEADS + hw] + adh) : -INFINITY;
    float m = logit;
    #pragma unroll
    for (int off = 32; off; off >>= 1) m = fmaxf(m, __shfl_xor(m, off));
    float ex = valid ? expf(logit - m) : 0.f;
    float z = ex;
    #pragma unroll
    for (int off = 32; off; off >>= 1) z += __shfl_xor(z, off);
    float al = ex / (z + 1e-16f);
    s_src[hw][lane] = s;
    s_al[hw][lane] = al;
    // wave-synchronous (same wave wrote these); 4x-unrolled gather
    int nk = deg + 1;
    int e = 0;
    for (; e + 3 < nk; e += 4) {
      int s0 = s_src[hw][e + 0], s1 = s_src[hw][e + 1];
      int s2 = s_src[hw][e + 2], s3 = s_src[hw][e + 3];
      float w0 = s_al[hw][e + 0], w1 = s_al[hw][e + 1];
      float w2 = s_al[hw][e + 2], w3 = s_al[hw][e + 3];
      ushort4 v0 = *(const ushort4*)&slab[(size_t)s0 * HID + c4];
      ushort4 v1 = *(const ushort4*)&slab[(size_t)s1 * HID + c4];
      ushort4 v2 = *(const ushort4*)&slab[(size_t)s2 * HID + c4];
      ushort4 v3 = *(const ushort4*)&slab[(size_t)s3 * HID + c4];
      a0 += w0 * bf2f(v0.x) + w1 * bf2f(v1.x) + w2 * bf2f(v2.x) + w3 * bf2f(v3.x);
      a1 += w0 * bf2f(v0.y) + w1 * bf2f(v1.y) + w2 * bf2f(v2.y) + w3 * bf2f(v3.y);
      a2 += w0 * bf2f(v0.z) + w1 * bf2f(v1.z) + w2 * bf2f(v2.z) + w3 * bf2f(v3.z);
      a3 += w0 * bf2f(v0.w) + w1 * bf2f(v1.w) + w2 * bf2f(v2.w) + w3 * bf2f(v3.w);
    }
    for (; e < nk; e++) {
      int se = s_src[hw][e];
      float ae = s_al[hw][e];
      ushort4 v = *(const ushort4*)&slab[(size_t)se * HID + c4];
      a0 += ae * bf2f(v.x); a1 += ae * bf2f(v.y);
      a2 += ae * bf2f(v.z); a3 += ae * bf2f(v.w);
    }
  } else {
    // generic chunked path (rare)
    float lself = lrelu02(a_src[i * NHEADS + hw] + adh);
    float m = lself;
    for (int e = beg + lane; e < end; e += 64)
      m = fmaxf(m, lrelu02(a_src[csr_src[e] * NHEADS + hw] + adh));
    #pragma unroll
    for (int off = 32; off; off >>= 1) m = fmaxf(m, __shfl_xor(m, off));
    float z = (lane == 0) ? expf(lself - m) : 0.f;
    for (int e = beg + lane; e < end; e += 64)
      z += expf(lrelu02(a_src[csr_src[e] * NHEADS + hw] + adh) - m);
    #pragma unroll
    for (int off = 32; off; off >>= 1) z += __shfl_xor(z, off);
    float iz = 1.f / (z + 1e-16f);
    {
      float ae = expf(lself - m) * iz;
      ushort4 v = *(const ushort4*)&slab[(size_t)i * HID + c4];
      a0 += ae * bf2f(v.x); a1 += ae * bf2f(v.y);
      a2 += ae * bf2f(v.z); a3 += ae * bf2f(v.w);
    }
    for (int base = beg; base < end; base += 64) {
      int mc = min(64, end - base);
      int s = (lane < mc) ? csr_src[base + lane] : 0;
      float al = (lane < mc)
                     ? expf(lrelu02(a_src[s * NHEADS + hw] + adh) - m) * iz
                     : 0.f;
      s_src[hw][lane] = s;
      s_al[hw][lane] = al;
      for (int e = 0; e < mc; e++) {
        int se = s_src[hw][e];
        float ae = s_al[hw][e];
        ushort4 v = *(const ushort4*)&slab[(size_t)se * HID + c4];
        a0 += ae * bf2f(v.x); a1 += ae * bf2f(v.y);
        a2 += ae * bf2f(v.z); a3 += ae * bf2f(v.w);
      }
    }
  }
  s_acc[hw][lane][0] = a0;
  s_acc[hw][lane][1] = a1;
  s_acc[hw][lane][2] = a2;
  s_acc[hw][lane][3] = a3;
  __syncthreads();
  int c = t;
  const float* f = (const float*)s_acc;
  float a = (f[c] + f[256 + c]) + (f[512 + c] + f[768 + c]);
  out[(size_t)i * HID + c] = fmaxf(a * 0.25f + bg[c], 0.f);
}

// ---------------------------------------------------------------------------
// Segmented global mean pool (batch sorted) + tiny head GEMM
// ---------------------------------------------------------------------------
#define POOL_CHUNK 50
__global__ __launch_bounds__(256) void pool_acc_k(const float* __restrict__ h3,
                                                  const int* __restrict__ batch,
                                                  float* __restrict__ pooled,
                                                  float* __restrict__ gcnt, int N) {
  int c = threadIdx.x;
  int i0 = blockIdx.x * POOL_CHUNK;
  int i1 = min(i0 + POOL_CHUNK, N);
  if (i0 >= N) return;
  float acc = 0.f;
  int cur = batch[i0];
  int cnt_local = 0;
  for (int i = i0; i < i1; i++) {
    int g = batch[i];
    if (g != cur) {
      atomicAdd(&pooled[cur * HID + c], acc);
      if (c == 0) atomicAdd(&gcnt[cur], (float)cnt_local);
      acc = 0.f;
      cnt_local = 0;
      cur = g;
    }
    acc += h3[(size_t)i * HID + c];
    cnt_local++;
  }
  atomicAdd(&pooled[cur * HID + c], acc);
  if (c == 0) atomicAdd(&gcnt[cur], (float)cnt_local);
}

__global__ __launch_bounds__(128) void head_k(const float* __restrict__ pooled,
                                              const float* __restrict__ gcnt,
                                              const float* __restrict__ W_heads,
                                              const float* __restrict__ b_heads,
                                              float* __restrict__ out) {
  int tid = threadIdx.x;
  if (tid >= NGRAPHS * 4) return;
  int g = tid >> 2, k = tid & 3;
  float invc = 1.f / fmaxf(gcnt[g], 1.f);
  float acc = 0.f;
  for (int c = 0; c < HID; c++) acc += pooled[g * HID + c] * W_heads[c * 4 + k];
  out[g * 4 + k] = acc * invc + b_heads[k];
}

// ---------------------------------------------------------------------------
extern "C" void kernel_launch(void* const* d_in, const int* in_sizes, int n_in,
                              void* d_out, int out_size, void* d_ws, size_t ws_size,
                              hipStream_t stream) {
  const float* x = (const float*)d_in[0];
  const int* ei = (const int*)d_in[1];
  const int* batch = (const int*)d_in[2];
  const float* W1 = (const float*)d_in[3];
  const float* b1 = (const float*)d_in[4];
  const float* W2 = (const float*)d_in[5];
  const float* b2 = (const float*)d_in[6];
  const float* Wg = (const float*)d_in[7];
  const float* att_src = (const float*)d_in[8];
  const float* att_dst = (const float*)d_in[9];
  const float* bg = (const float*)d_in[10];
  const float* W_heads = (const float*)d_in[11];
  const float* b_heads = (const float*)d_in[12];
  float* out = (float*)d_out;

  const int N = in_sizes[0] / IN_DIM;   // 10000
  const int E = in_sizes[1] / 2;        // 160000
  const int* src = ei;
  const int* dst = ei + E;

  const int NFM = N / 16;               // 625 A-row fragments
  const int NFMP = ((N + 63) / 64) * 4; // padded to block multiple (628)

  // workspace layout (256B aligned)
  char* ws = (char*)d_ws;
  size_t off = 0;
  auto take = [&](size_t bytes) -> char* {
    char* p = ws + off;
    off = (off + bytes + 255) & ~(size_t)255;
    return p;
  };
  int* cnt      = (int*)take((size_t)N * 4);
  int* row_ptr  = (int*)take((size_t)(N + 1) * 4);
  int* cursor   = (int*)take((size_t)N * 4);
  int* csr_src  = (int*)take((size_t)E * 4);
  float* dinv   = (float*)take((size_t)N * 4);
  float* a_srcv = (float*)take((size_t)N * NHEADS * 4);
  float* a_dstv = (float*)take((size_t)N * NHEADS * 4);
  float* w_s    = (float*)take((size_t)HID * NHEADS * 4);
  float* w_d    = (float*)take((size_t)HID * NHEADS * 4);
  float* pooled = (float*)take((size_t)NGRAPHS * HID * 4 + NGRAPHS * 4);
  float* gcnt   = pooled + NGRAPHS * HID;
  u16*   tb     = (u16*)take((size_t)N * HID * 2);            // bf16 GEMM out
  float* h3     = (float*)take((size_t)N * HID * 4);
  u16*   hgT    = (u16*)take((size_t)N * NHEADS * HID * 2);
  // packed operands (u16): frag stride = KT*1024 u16
  u16*   xp     = (u16*)take((size_t)NFMP * 4 * 1024 * 2);    // K=128, KT=4
  u16*   h1p    = (u16*)take((size_t)NFMP * 8 * 1024 * 2);    // K=256, KT=8
  u16*   h2p    = (u16*)take((size_t)NFMP * 8 * 1024 * 2);
  u16*   w1p    = (u16*)take((size_t)16 * 4 * 1024 * 2);
  u16*   w2p    = (u16*)take((size_t)16 * 8 * 1024 * 2);
  u16*   wgp    = (u16*)take((size_t)64 * 8 * 1024 * 2);

  hipMemsetAsync(cnt, 0, (size_t)N * 4, stream);
  hipMemsetAsync(cursor, 0, (size_t)N * 4, stream);
  hipMemsetAsync(pooled, 0, (size_t)NGRAPHS * HID * 4 + NGRAPHS * 4, stream);

  int eb = (E + 255) / 256;
  count_edges_k<<<eb, 256, 0, stream>>>(dst, cnt, E);
  scan_k<<<1, 1024, 0, stream>>>(cnt, row_ptr, dinv, N);
  fill_csr_k<<<eb, 256, 0, stream>>>(src, dst, row_ptr, cursor, csr_src, E);
  watt_k<<<HID, 256, 0, stream>>>(Wg, att_src, att_dst, w_s, w_d);

  // pack inputs/weights
  pack_a_k<<<(NFM * 4 + 3) / 4, 256, 0, stream>>>(x, xp, IN_DIM, 4, NFM);
  pack_b_k<<<(16 * 4 + 3) / 4, 256, 0, stream>>>(W1, w1p, HID, 4, 16);
  pack_b_k<<<(16 * 8 + 3) / 4, 256, 0, stream>>>(W2, w2p, HID, 8, 16);
  pack_b_k<<<(64 * 8 + 3) / 4, 256, 0, stream>>>(Wg, wgp, NHEADS * HID, 8, 64);

  int mg64 = (N + 63) / 64;
  // layer 1: tb = x @ W1 (bf16) ; h1p = pack(relu(agg(tb) + b1))
  mfma_gemm_k<4, 0, true><<<dim3(4, mg64), 256, 0, stream>>>(xp, w1p, tb, N, N);
  gcn_agg_k<false, true><<<N, 256, 0, stream>>>(tb, row_ptr, csr_src, dinv, b1,
                                                h1p, nullptr, nullptr, nullptr, nullptr);
  // layer 2: tb = h1 @ W2 (bf16) ; h2p (hi only) + fused logits
  mfma_gemm_k<8, 0, true><<<dim3(4, mg64), 256, 0, stream>>>(h1p, w2p, tb, N, N);
  gcn_agg_k<true, false><<<N, 256, 0, stream>>>(tb, row_ptr, csr_src, dinv, b2,
                                                h2p, w_s, w_d, a_srcv, a_dstv);
  // GAT: hgT (bf16 head-major) = h2 @ Wg (2-term, A-hi only)
  mfma_gemm_k<8, 1, false><<<dim3(16, mg64), 256, 0, stream>>>(h2p, wgp, hgT, N, N);
  gat_agg_k<<<N, 256, 0, stream>>>(hgT, row_ptr, csr_src, a_srcv, a_dstv, bg, h3, N);
  // pool + heads
  int pb = (N + POOL_CHUNK - 1) / POOL_CHUNK;
  pool_acc_k<<<pb, 256, 0, stream>>>(h3, batch, pooled, gcnt, N);
  head_k<<<1, 128, 0, stream>>>(pooled, gcnt, W_heads, b_heads, out);
}

// Round 7
// 197.150 us; speedup vs baseline: 1.9560x; 1.1792x over previous
//
#include <hip/hip_runtime.h>
#include <cmath>

// Problem constants (from reference)
#define IN_DIM 128
#define HID 256
#define NHEADS 4
#define NGRAPHS 32

typedef unsigned short u16;
typedef __attribute__((ext_vector_type(8))) short bfrag8;   // 8 bf16 (4 VGPRs)
typedef __attribute__((ext_vector_type(4))) float f32x4;    // MFMA acc

// bf16 helpers (RNE)
__device__ __forceinline__ u16 f2bf(float x) {
  unsigned u = __float_as_uint(x);
  unsigned r = (u + 0x7fffu + ((u >> 16) & 1u)) >> 16;
  return (u16)r;
}
__device__ __forceinline__ float bf2f(u16 v) {
  return __uint_as_float(((unsigned)v) << 16);
}
__device__ __forceinline__ float lof(unsigned u) { return __uint_as_float(u << 16); }
__device__ __forceinline__ float hif(unsigned u) { return __uint_as_float(u & 0xffff0000u); }
__device__ __forceinline__ float lrelu02(float x) { return x > 0.f ? x : 0.2f * x; }

// ---------------------------------------------------------------------------
// CSR build
// ---------------------------------------------------------------------------
__global__ __launch_bounds__(256) void count_edges_k(const int* __restrict__ dst,
                                                     int* __restrict__ cnt, int E) {
  int i = blockIdx.x * 256 + threadIdx.x;
  if (i < E) atomicAdd(&cnt[dst[i]], 1);
}

// single-block shuffle-based scan (3 barriers per 1024-chunk)
__global__ __launch_bounds__(1024) void scan_k(const int* __restrict__ cnt,
                                               int* __restrict__ row_ptr,
                                               float* __restrict__ dinv, int n) {
  __shared__ int s_w[16];
  __shared__ int s_tot;
  int tid = threadIdx.x;
  int wv = tid >> 6, lane = tid & 63;
  int carry = 0;
  int nch = (n + 1023) >> 10;
  for (int c = 0; c < nch; c++) {
    int i = (c << 10) + tid;
    int v = (i < n) ? cnt[i] : 0;
    int incl = v;
    #pragma unroll
    for (int off = 1; off < 64; off <<= 1) {
      int t = __shfl_up(incl, off);
      if (lane >= off) incl += t;
    }
    if (lane == 63) s_w[wv] = incl;
    __syncthreads();
    if (tid < 16) {
      int sv = s_w[tid];
      int si = sv;
      #pragma unroll
      for (int off = 1; off < 16; off <<= 1) {
        int t = __shfl_up(si, off, 16);
        if (tid >= off) si += t;
      }
      s_w[tid] = si - sv;        // exclusive prefix of wave sums
      if (tid == 15) s_tot = si; // block total
    }
    __syncthreads();
    int excl = incl - v + s_w[wv] + carry;
    if (i < n) {
      row_ptr[i] = excl;
      dinv[i] = rsqrtf((float)(v + 1));
    }
    carry += s_tot;
    __syncthreads();
  }
  if (tid == 0) row_ptr[n] = carry;
}

__global__ __launch_bounds__(256) void fill_csr_k(const int* __restrict__ src,
                                                  const int* __restrict__ dst,
                                                  const int* __restrict__ row_ptr,
                                                  int* __restrict__ cursor,
                                                  int* __restrict__ csr_src, int E) {
  int i = blockIdx.x * 256 + threadIdx.x;
  if (i < E) {
    int d = dst[i];
    int p = atomicAdd(&cursor[d], 1);
    csr_src[row_ptr[d] + p] = src[i];
  }
}

// ---------------------------------------------------------------------------
// Fused prep: pack x / W1 / W2 / Wg into MFMA fragment order (split hi/lo)
// + attention weight projections (watt).  Branch on block ranges.
// Packed layout (u16): [(frag*KT + kt)*1024 + hl*512 + lane*8 + j]
// ---------------------------------------------------------------------------
__device__ void pack_a_dev(const float* __restrict__ A, u16* __restrict__ Ap,
                           int K, int KT, int wid, int lane) {
  int fm = wid / KT, kt = wid - fm * KT;
  int m = fm * 16 + (lane & 15);
  int kb = kt * 32 + (lane >> 4) * 8;
  const float* src = A + (size_t)m * K + kb;
  float4 v0 = *(const float4*)src;
  float4 v1 = *(const float4*)(src + 4);
  float vv[8] = {v0.x, v0.y, v0.z, v0.w, v1.x, v1.y, v1.z, v1.w};
  u16 hi[8], lo[8];
  #pragma unroll
  for (int j = 0; j < 8; j++) {
    u16 h = f2bf(vv[j]);
    hi[j] = h;
    lo[j] = f2bf(vv[j] - bf2f(h));
  }
  u16* dstp = Ap + ((size_t)fm * KT + kt) * 1024 + lane * 8;
  *(ushort4*)(dstp)       = make_ushort4(hi[0], hi[1], hi[2], hi[3]);
  *(ushort4*)(dstp + 4)   = make_ushort4(hi[4], hi[5], hi[6], hi[7]);
  *(ushort4*)(dstp + 512) = make_ushort4(lo[0], lo[1], lo[2], lo[3]);
  *(ushort4*)(dstp + 516) = make_ushort4(lo[4], lo[5], lo[6], lo[7]);
}

__device__ void pack_b_dev(const float* __restrict__ B, u16* __restrict__ Bp,
                           int N, int KT, int wid, int lane) {
  int fn = wid / KT, kt = wid - fn * KT;
  int n = fn * 16 + (lane & 15);
  int kb = kt * 32 + (lane >> 4) * 8;
  float vv[8];
  #pragma unroll
  for (int j = 0; j < 8; j++) vv[j] = B[(size_t)(kb + j) * N + n];
  u16 hi[8], lo[8];
  #pragma unroll
  for (int j = 0; j < 8; j++) {
    u16 h = f2bf(vv[j]);
    hi[j] = h;
    lo[j] = f2bf(vv[j] - bf2f(h));
  }
  u16* dstp = Bp + ((size_t)fn * KT + kt) * 1024 + lane * 8;
  *(ushort4*)(dstp)       = make_ushort4(hi[0], hi[1], hi[2], hi[3]);
  *(ushort4*)(dstp + 4)   = make_ushort4(hi[4], hi[5], hi[6], hi[7]);
  *(ushort4*)(dstp + 512) = make_ushort4(lo[0], lo[1], lo[2], lo[3]);
  *(ushort4*)(dstp + 516) = make_ushort4(lo[4], lo[5], lo[6], lo[7]);
}

__global__ __launch_bounds__(256) void prep_k(const float* __restrict__ x,
                                              const float* __restrict__ W1,
                                              const float* __restrict__ W2,
                                              const float* __restrict__ Wg,
                                              const float* __restrict__ att_src,
                                              const float* __restrict__ att_dst,
                                              u16* __restrict__ xp,
                                              u16* __restrict__ w1p,
                                              u16* __restrict__ w2p,
                                              u16* __restrict__ wgp,
                                              float* __restrict__ w_s,
                                              float* __restrict__ w_d, int NFM) {
  __shared__ float red_s[4][NHEADS];
  __shared__ float red_d[4][NHEADS];
  int b = blockIdx.x;
  int tid = threadIdx.x;
  int lane = tid & 63;
  int XB = NFM;                 // x-pack blocks (4 wids each)
  if (b < XB) {
    int wid = b * 4 + (tid >> 6);
    if (wid < NFM * 4) pack_a_dev(x, xp, IN_DIM, 4, wid, lane);
  } else if (b < XB + 16) {
    pack_b_dev(W1, w1p, HID, 4, (b - XB) * 4 + (tid >> 6), lane);
  } else if (b < XB + 48) {
    pack_b_dev(W2, w2p, HID, 8, (b - XB - 16) * 4 + (tid >> 6), lane);
  } else if (b < XB + 176) {
    pack_b_dev(Wg, wgp, NHEADS * HID, 8, (b - XB - 48) * 4 + (tid >> 6), lane);
  } else {
    // watt: w_s[k][h] = <Wg[k, h*256:...], att_src[h]>
    int k = b - (XB + 176);
    int c = tid, wvv = c >> 6, ln = c & 63;
    #pragma unroll
    for (int h = 0; h < NHEADS; h++) {
      float w = Wg[(size_t)k * (NHEADS * HID) + h * HID + c];
      float vs = w * att_src[h * HID + c];
      float vd = w * att_dst[h * HID + c];
      #pragma unroll
      for (int off = 32; off; off >>= 1) {
        vs += __shfl_xor(vs, off);
        vd += __shfl_xor(vd, off);
      }
      if (ln == 0) { red_s[wvv][h] = vs; red_d[wvv][h] = vd; }
    }
    __syncthreads();
    if (c < NHEADS)
      w_s[k * NHEADS + c] = red_s[0][c] + red_s[1][c] + red_s[2][c] + red_s[3][c];
    else if (c < 2 * NHEADS) {
      int h = c - NHEADS;
      w_d[k * NHEADS + h] = red_d[0][h] + red_d[1][h] + red_d[2][h] + red_d[3][h];
    }
  }
}

// ---------------------------------------------------------------------------
// Split-bf16 MFMA GEMM, operands pre-packed, no LDS / no barriers.
// Block = 4 waves (2x2); wave = 32x32 output; block tile 64x64.
// ALO: 3-term (~fp32) vs 2-term (A-hi only).  Output bf16 row-major [M][LDC].
// ---------------------------------------------------------------------------
template <int KT, int LDC, bool ALO>
__global__ __launch_bounds__(256) void mfma_gemm_k(const u16* __restrict__ Ap,
                                                   const u16* __restrict__ Bp,
                                                   u16* __restrict__ Cb, int M) {
  int tid = threadIdx.x;
  int w = tid >> 6, lane = tid & 63;
  int wm = w >> 1, wn = w & 1;
  int fm0 = blockIdx.y * 4 + wm * 2;
  int fn0 = blockIdx.x * 4 + wn * 2;
  f32x4 acc[2][2] = {};
  #pragma unroll
  for (int kt = 0; kt < KT; kt++) {
    bfrag8 a_hi[2], a_lo[2], b_hi[2], b_lo[2];
    #pragma unroll
    for (int f = 0; f < 2; f++) {
      const u16* pa = Ap + ((size_t)(fm0 + f) * KT + kt) * 1024 + lane * 8;
      a_hi[f] = *(const bfrag8*)pa;
      if constexpr (ALO) a_lo[f] = *(const bfrag8*)(pa + 512);
      const u16* pb = Bp + ((size_t)(fn0 + f) * KT + kt) * 1024 + lane * 8;
      b_hi[f] = *(const bfrag8*)pb;
      b_lo[f] = *(const bfrag8*)(pb + 512);
    }
    #pragma unroll
    for (int f = 0; f < 2; f++) {
      #pragma unroll
      for (int g = 0; g < 2; g++) {
        acc[f][g] = __builtin_amdgcn_mfma_f32_16x16x32_bf16(a_hi[f], b_hi[g], acc[f][g], 0, 0, 0);
        acc[f][g] = __builtin_amdgcn_mfma_f32_16x16x32_bf16(a_hi[f], b_lo[g], acc[f][g], 0, 0, 0);
        if constexpr (ALO)
          acc[f][g] = __builtin_amdgcn_mfma_f32_16x16x32_bf16(a_lo[f], b_hi[g], acc[f][g], 0, 0, 0);
      }
    }
  }
  int r0 = (lane >> 4) * 4;
  int cl = lane & 15;
  #pragma unroll
  for (int f = 0; f < 2; f++) {
    #pragma unroll
    for (int g = 0; g < 2; g++) {
      int col = (fn0 + g) * 16 + cl;
      #pragma unroll
      for (int r = 0; r < 4; r++) {
        int row = (fm0 + f) * 16 + r0 + r;
        if (row < M) Cb[(size_t)row * LDC + col] = f2bf(acc[f][g][r]);
      }
    }
  }
}

// ---------------------------------------------------------------------------
// GCN aggregation, one WAVE per node (no LDS, no barriers).
// Lane owns 4 channels (uint2 bf16 loads), unroll-4 edge gather.
// v = relu(agg + b); packed split-bf16 out; LOGITS fused for layer 2.
// ---------------------------------------------------------------------------
template <bool LOGITS, bool PACK_LO>
__global__ __launch_bounds__(256) void gcn_agg_k(const u16* __restrict__ t,
                                                 const int* __restrict__ row_ptr,
                                                 const int* __restrict__ csr_src,
                                                 const float* __restrict__ dinv,
                                                 const float* __restrict__ bias,
                                                 u16* __restrict__ apack,
                                                 const float* __restrict__ w_s,
                                                 const float* __restrict__ w_d,
                                                 float4* __restrict__ a_src4,
                                                 float4* __restrict__ a_dst4, int N) {
  int wv = threadIdx.x >> 6, lane = threadIdx.x & 63;
  int i = blockIdx.x * 4 + wv;
  if (i >= N) return;
  float di = dinv[i];
  int c4 = lane * 4;
  int beg = row_ptr[i], end = row_ptr[i + 1];
  float a0, a1, a2, a3;
  {
    uint2 u = *(const uint2*)&t[(size_t)i * HID + c4];
    float w = di * di;
    a0 = w * lof(u.x); a1 = w * hif(u.x); a2 = w * lof(u.y); a3 = w * hif(u.y);
  }
  int e = beg;
  for (; e + 3 < end; e += 4) {
    int s0 = csr_src[e + 0], s1 = csr_src[e + 1];
    int s2 = csr_src[e + 2], s3 = csr_src[e + 3];
    float w0 = dinv[s0] * di, w1 = dinv[s1] * di;
    float w2 = dinv[s2] * di, w3 = dinv[s3] * di;
    uint2 u0 = *(const uint2*)&t[(size_t)s0 * HID + c4];
    uint2 u1 = *(const uint2*)&t[(size_t)s1 * HID + c4];
    uint2 u2 = *(const uint2*)&t[(size_t)s2 * HID + c4];
    uint2 u3 = *(const uint2*)&t[(size_t)s3 * HID + c4];
    a0 += w0 * lof(u0.x) + w1 * lof(u1.x) + w2 * lof(u2.x) + w3 * lof(u3.x);
    a1 += w0 * hif(u0.x) + w1 * hif(u1.x) + w2 * hif(u2.x) + w3 * hif(u3.x);
    a2 += w0 * lof(u0.y) + w1 * lof(u1.y) + w2 * lof(u2.y) + w3 * lof(u3.y);
    a3 += w0 * hif(u0.y) + w1 * hif(u1.y) + w2 * hif(u2.y) + w3 * hif(u3.y);
  }
  for (; e < end; e++) {
    int s = csr_src[e];
    float w = dinv[s] * di;
    uint2 u = *(const uint2*)&t[(size_t)s * HID + c4];
    a0 += w * lof(u.x); a1 += w * hif(u.x); a2 += w * lof(u.y); a3 += w * hif(u.y);
  }
  float4 bv = *(const float4*)&bias[c4];
  float v0 = fmaxf(a0 + bv.x, 0.f), v1 = fmaxf(a1 + bv.y, 0.f);
  float v2 = fmaxf(a2 + bv.z, 0.f), v3 = fmaxf(a3 + bv.w, 0.f);
  // pack split-bf16 (KT=8 layout)
  {
    int fm = i >> 4, kt = c4 >> 5;
    int pl = (i & 15) + 16 * ((c4 >> 3) & 3);
    int j0 = c4 & 7;
    size_t base = ((size_t)fm * 8 + kt) * 1024 + pl * 8 + j0;
    u16 h0 = f2bf(v0), h1 = f2bf(v1), h2 = f2bf(v2), h3 = f2bf(v3);
    *(ushort4*)&apack[base] = make_ushort4(h0, h1, h2, h3);
    if constexpr (PACK_LO)
      *(ushort4*)&apack[base + 512] =
          make_ushort4(f2bf(v0 - bf2f(h0)), f2bf(v1 - bf2f(h1)),
                       f2bf(v2 - bf2f(h2)), f2bf(v3 - bf2f(h3)));
  }
  if constexpr (LOGITS) {
    const float4* ws4 = (const float4*)w_s;
    const float4* wd4 = (const float4*)w_d;
    float4 s0 = ws4[c4 + 0], s1 = ws4[c4 + 1], s2 = ws4[c4 + 2], s3 = ws4[c4 + 3];
    float4 d0 = wd4[c4 + 0], d1 = wd4[c4 + 1], d2 = wd4[c4 + 2], d3 = wd4[c4 + 3];
    float ps0 = v0 * s0.x + v1 * s1.x + v2 * s2.x + v3 * s3.x;
    float ps1 = v0 * s0.y + v1 * s1.y + v2 * s2.y + v3 * s3.y;
    float ps2 = v0 * s0.z + v1 * s1.z + v2 * s2.z + v3 * s3.z;
    float ps3 = v0 * s0.w + v1 * s1.w + v2 * s2.w + v3 * s3.w;
    float pd0 = v0 * d0.x + v1 * d1.x + v2 * d2.x + v3 * d3.x;
    float pd1 = v0 * d0.y + v1 * d1.y + v2 * d2.y + v3 * d3.y;
    float pd2 = v0 * d0.z + v1 * d1.z + v2 * d2.z + v3 * d3.z;
    float pd3 = v0 * d0.w + v1 * d1.w + v2 * d2.w + v3 * d3.w;
    #pragma unroll
    for (int off = 32; off; off >>= 1) {
      ps0 += __shfl_xor(ps0, off); ps1 += __shfl_xor(ps1, off);
      ps2 += __shfl_xor(ps2, off); ps3 += __shfl_xor(ps3, off);
      pd0 += __shfl_xor(pd0, off); pd1 += __shfl_xor(pd1, off);
      pd2 += __shfl_xor(pd2, off); pd3 += __shfl_xor(pd3, off);
    }
    if (lane == 0) {
      a_src4[i] = make_float4(ps0, ps1, ps2, ps3);
      a_dst4[i] = make_float4(pd0, pd1, pd2, pd3);
    }
  }
}

// ---------------------------------------------------------------------------
// GAT aggregation, one WAVE per node, node-major hgT [n][1024] bf16.
// Softmax (4 heads) in registers; lane owns head lane>>4 / 16 channels;
// head-mean via shfl_xor(16/32); no barriers.
// ---------------------------------------------------------------------------
#define ACC8(U, AW, O)                                         \
  acc[O + 0] += (AW) * lof((U).x); acc[O + 1] += (AW) * hif((U).x); \
  acc[O + 2] += (AW) * lof((U).y); acc[O + 3] += (AW) * hif((U).y); \
  acc[O + 4] += (AW) * lof((U).z); acc[O + 5] += (AW) * hif((U).z); \
  acc[O + 6] += (AW) * lof((U).w); acc[O + 7] += (AW) * hif((U).w);

__global__ __launch_bounds__(256) void gat_agg_k(const u16* __restrict__ hgT,
                                                 const int* __restrict__ row_ptr,
                                                 const int* __restrict__ csr_src,
                                                 const float4* __restrict__ a_src4,
                                                 const float4* __restrict__ a_dst4,
                                                 const float* __restrict__ bg,
                                                 float* __restrict__ out, int N) {
  __shared__ int s_src[4][64];
  __shared__ float s_al[4][NHEADS][65];
  int wv = threadIdx.x >> 6, lane = threadIdx.x & 63;
  int i = blockIdx.x * 4 + wv;
  if (i >= N) return;
  int beg = row_ptr[i], end = row_ptr[i + 1];
  int deg = end - beg;
  float4 ad = a_dst4[i];
  int hw = lane >> 4;
  float acc[16];
  #pragma unroll
  for (int j = 0; j < 16; j++) acc[j] = 0.f;
  const u16* rowbase = hgT + (size_t)lane * 16;  // + se*1024

  int nk;
  if (deg <= 63) {
    int s = (lane < deg) ? csr_src[beg + lane] : i;
    bool valid = (lane <= deg);
    float4 as = a_src4[s];
    float l0 = valid ? lrelu02(as.x + ad.x) : -INFINITY;
    float l1 = valid ? lrelu02(as.y + ad.y) : -INFINITY;
    float l2 = valid ? lrelu02(as.z + ad.z) : -INFINITY;
    float l3 = valid ? lrelu02(as.w + ad.w) : -INFINITY;
    float m0 = l0, m1 = l1, m2 = l2, m3 = l3;
    #pragma unroll
    for (int off = 32; off; off >>= 1) {
      m0 = fmaxf(m0, __shfl_xor(m0, off)); m1 = fmaxf(m1, __shfl_xor(m1, off));
      m2 = fmaxf(m2, __shfl_xor(m2, off)); m3 = fmaxf(m3, __shfl_xor(m3, off));
    }
    float e0 = valid ? expf(l0 - m0) : 0.f;
    float e1 = valid ? expf(l1 - m1) : 0.f;
    float e2 = valid ? expf(l2 - m2) : 0.f;
    float e3 = valid ? expf(l3 - m3) : 0.f;
    float z0 = e0, z1 = e1, z2 = e2, z3 = e3;
    #pragma unroll
    for (int off = 32; off; off >>= 1) {
      z0 += __shfl_xor(z0, off); z1 += __shfl_xor(z1, off);
      z2 += __shfl_xor(z2, off); z3 += __shfl_xor(z3, off);
    }
    s_src[wv][lane] = s;
    s_al[wv][0][lane] = e0 / (z0 + 1e-16f);
    s_al[wv][1][lane] = e1 / (z1 + 1e-16f);
    s_al[wv][2][lane] = e2 / (z2 + 1e-16f);
    s_al[wv][3][lane] = e3 / (z3 + 1e-16f);
    nk = deg + 1;
    // wave-synchronous gather, unroll 2
    int e = 0;
    for (; e + 1 < nk; e += 2) {
      int sa = s_src[wv][e], sb = s_src[wv][e + 1];
      float awa = s_al[wv][hw][e], awb = s_al[wv][hw][e + 1];
      const uint4* ra = (const uint4*)(rowbase + (size_t)sa * 1024);
      const uint4* rb = (const uint4*)(rowbase + (size_t)sb * 1024);
      uint4 ua0 = ra[0], ua1 = ra[1];
      uint4 ub0 = rb[0], ub1 = rb[1];
      ACC8(ua0, awa, 0); ACC8(ua1, awa, 8);
      ACC8(ub0, awb, 0); ACC8(ub1, awb, 8);
    }
    if (e < nk) {
      int sa = s_src[wv][e];
      float awa = s_al[wv][hw][e];
      const uint4* ra = (const uint4*)(rowbase + (size_t)sa * 1024);
      uint4 ua0 = ra[0], ua1 = ra[1];
      ACC8(ua0, awa, 0); ACC8(ua1, awa, 8);
    }
  } else {
    // generic path (deg > 63): strided softmax, chunked gather
    float4 asi = a_src4[i];
    float ls0 = lrelu02(asi.x + ad.x), ls1 = lrelu02(asi.y + ad.y);
    float ls2 = lrelu02(asi.z + ad.z), ls3 = lrelu02(asi.w + ad.w);
    float m0 = ls0, m1 = ls1, m2 = ls2, m3 = ls3;
    for (int e = beg + lane; e < end; e += 64) {
      float4 as = a_src4[csr_src[e]];
      m0 = fmaxf(m0, lrelu02(as.x + ad.x)); m1 = fmaxf(m1, lrelu02(as.y + ad.y));
      m2 = fmaxf(m2, lrelu02(as.z + ad.z)); m3 = fmaxf(m3, lrelu02(as.w + ad.w));
    }
    #pragma unroll
    for (int off = 32; off; off >>= 1) {
      m0 = fmaxf(m0, __shfl_xor(m0, off)); m1 = fmaxf(m1, __shfl_xor(m1, off));
      m2 = fmaxf(m2, __shfl_xor(m2, off)); m3 = fmaxf(m3, __shfl_xor(m3, off));
    }
    float z0 = (lane == 0) ? expf(ls0 - m0) : 0.f;
    float z1 = (lane == 0) ? expf(ls1 - m1) : 0.f;
    float z2 = (lane == 0) ? expf(ls2 - m2) : 0.f;
    float z3 = (lane == 0) ? expf(ls3 - m3) : 0.f;
    for (int e = beg + lane; e < end; e += 64) {
      float4 as = a_src4[csr_src[e]];
      z0 += expf(lrelu02(as.x + ad.x) - m0); z1 += expf(lrelu02(as.y + ad.y) - m1);
      z2 += expf(lrelu02(as.z + ad.z) - m2); z3 += expf(lrelu02(as.w + ad.w) - m3);
    }
    #pragma unroll
    for (int off = 32; off; off >>= 1) {
      z0 += __shfl_xor(z0, off); z1 += __shfl_xor(z1, off);
      z2 += __shfl_xor(z2, off); z3 += __shfl_xor(z3, off);
    }
    float iz0 = 1.f / (z0 + 1e-16f), iz1 = 1.f / (z1 + 1e-16f);
    float iz2 = 1.f / (z2 + 1e-16f), iz3 = 1.f / (z3 + 1e-16f);
    // self contribution
    {
      float w0 = expf(ls0 - m0) * iz0, w1 = expf(ls1 - m1) * iz1;
      float w2 = expf(ls2 - m2) * iz2, w3 = expf(ls3 - m3) * iz3;
      float aw = hw == 0 ? w0 : hw == 1 ? w1 : hw == 2 ? w2 : w3;
      const uint4* r = (const uint4*)(rowbase + (size_t)i * 1024);
      uint4 u0 = r[0], u1 = r[1];
      ACC8(u0, aw, 0); ACC8(u1, aw, 8);
    }
    for (int base = beg; base < end; base += 64) {
      int mc = min(64, end - base);
      if (lane < mc) {
        int s = csr_src[base + lane];
        float4 as = a_src4[s];
        s_src[wv][lane] = s;
        s_al[wv][0][lane] = expf(lrelu02(as.x + ad.x) - m0) * iz0;
        s_al[wv][1][lane] = expf(lrelu02(as.y + ad.y) - m1) * iz1;
        s_al[wv][2][lane] = expf(lrelu02(as.z + ad.z) - m2) * iz2;
        s_al[wv][3][lane] = expf(lrelu02(as.w + ad.w) - m3) * iz3;
      }
      for (int e = 0; e < mc; e++) {
        int sa = s_src[wv][e];
        float awa = s_al[wv][hw][e];
        const uint4* ra = (const uint4*)(rowbase + (size_t)sa * 1024);
        uint4 ua0 = ra[0], ua1 = ra[1];
        ACC8(ua0, awa, 0); ACC8(ua1, awa, 8);
      }
    }
  }
  // head-mean in-register: sum lanes {l, l^16, l^32, l^48}
  #pragma unroll
  for (int j = 0; j < 16; j++) {
    acc[j] += __shfl_xor(acc[j], 16);
    acc[j] += __shfl_xor(acc[j], 32);
  }
  if (lane < 16) {
    int cb = lane * 16;
    float o[16];
    #pragma unroll
    for (int j = 0; j < 16; j++)
      o[j] = fmaxf(acc[j] * 0.25f + bg[cb + j], 0.f);
    float* op = out + (size_t)i * HID + cb;
    *(float4*)(op + 0)  = make_float4(o[0], o[1], o[2], o[3]);
    *(float4*)(op + 4)  = make_float4(o[4], o[5], o[6], o[7]);
    *(float4*)(op + 8)  = make_float4(o[8], o[9], o[10], o[11]);
    *(float4*)(op + 12) = make_float4(o[12], o[13], o[14], o[15]);
  }
}

// ---------------------------------------------------------------------------
// Segmented global mean pool (batch sorted) + tiny head GEMM
// ---------------------------------------------------------------------------
#define POOL_CHUNK 50
__global__ __launch_bounds__(256) void pool_acc_k(const float* __restrict__ h3,
                                                  const int* __restrict__ batch,
                                                  float* __restrict__ pooled,
                                                  float* __restrict__ gcnt, int N) {
  int c = threadIdx.x;
  int i0 = blockIdx.x * POOL_CHUNK;
  int i1 = min(i0 + POOL_CHUNK, N);
  if (i0 >= N) return;
  float acc = 0.f;
  int cur = batch[i0];
  int cnt_local = 0;
  for (int i = i0; i < i1; i++) {
    int g = batch[i];
    if (g != cur) {
      atomicAdd(&pooled[cur * HID + c], acc);
      if (c == 0) atomicAdd(&gcnt[cur], (float)cnt_local);
      acc = 0.f;
      cnt_local = 0;
      cur = g;
    }
    acc += h3[(size_t)i * HID + c];
    cnt_local++;
  }
  atomicAdd(&pooled[cur * HID + c], acc);
  if (c == 0) atomicAdd(&gcnt[cur], (float)cnt_local);
}

__global__ __launch_bounds__(128) void head_k(const float* __restrict__ pooled,
                                              const float* __restrict__ gcnt,
                                              const float* __restrict__ W_heads,
                                              const float* __restrict__ b_heads,
                                              float* __restrict__ out) {
  int tid = threadIdx.x;
  if (tid >= NGRAPHS * 4) return;
  int g = tid >> 2, k = tid & 3;
  float invc = 1.f / fmaxf(gcnt[g], 1.f);
  float acc = 0.f;
  for (int c = 0; c < HID; c++) acc += pooled[g * HID + c] * W_heads[c * 4 + k];
  out[g * 4 + k] = acc * invc + b_heads[k];
}

// ---------------------------------------------------------------------------
extern "C" void kernel_launch(void* const* d_in, const int* in_sizes, int n_in,
                              void* d_out, int out_size, void* d_ws, size_t ws_size,
                              hipStream_t stream) {
  const float* x = (const float*)d_in[0];
  const int* ei = (const int*)d_in[1];
  const int* batch = (const int*)d_in[2];
  const float* W1 = (const float*)d_in[3];
  const float* b1 = (const float*)d_in[4];
  const float* W2 = (const float*)d_in[5];
  const float* b2 = (const float*)d_in[6];
  const float* Wg = (const float*)d_in[7];
  const float* att_src = (const float*)d_in[8];
  const float* att_dst = (const float*)d_in[9];
  const float* bg = (const float*)d_in[10];
  const float* W_heads = (const float*)d_in[11];
  const float* b_heads = (const float*)d_in[12];
  float* out = (float*)d_out;

  const int N = in_sizes[0] / IN_DIM;   // 10000
  const int E = in_sizes[1] / 2;        // 160000
  const int* src = ei;
  const int* dst = ei + E;

  const int NFM = N / 16;               // 625
  const int NFMP = ((N + 63) / 64) * 4; // 628

  // workspace layout (256B aligned); cnt|cursor|pooled contiguous for 1 memset
  char* ws = (char*)d_ws;
  size_t off = 0;
  auto take = [&](size_t bytes) -> char* {
    char* p = ws + off;
    off = (off + bytes + 255) & ~(size_t)255;
    return p;
  };
  int* cnt      = (int*)take((size_t)N * 4);
  int* cursor   = (int*)take((size_t)N * 4);
  float* pooled = (float*)take((size_t)NGRAPHS * HID * 4 + NGRAPHS * 4);
  float* gcnt   = pooled + NGRAPHS * HID;
  size_t zero_span = off;               // memset from cnt over this span
  int* row_ptr  = (int*)take((size_t)(N + 1) * 4);
  int* csr_src  = (int*)take((size_t)E * 4);
  float* dinv   = (float*)take((size_t)N * 4);
  float4* a_src4 = (float4*)take((size_t)N * 16);
  float4* a_dst4 = (float4*)take((size_t)N * 16);
  float* w_s    = (float*)take((size_t)HID * NHEADS * 4);
  float* w_d    = (float*)take((size_t)HID * NHEADS * 4);
  u16*   tb     = (u16*)take((size_t)N * HID * 2);
  float* h3     = (float*)take((size_t)N * HID * 4);
  u16*   hgT    = (u16*)take((size_t)N * NHEADS * HID * 2);   // node-major [n][1024]
  u16*   xp     = (u16*)take((size_t)NFMP * 4 * 1024 * 2);
  u16*   h1p    = (u16*)take((size_t)NFMP * 8 * 1024 * 2);
  u16*   h2p    = (u16*)take((size_t)NFMP * 8 * 1024 * 2);
  u16*   w1p    = (u16*)take((size_t)16 * 4 * 1024 * 2);
  u16*   w2p    = (u16*)take((size_t)16 * 8 * 1024 * 2);
  u16*   wgp    = (u16*)take((size_t)64 * 8 * 1024 * 2);

  hipMemsetAsync(cnt, 0, zero_span, stream);

  int eb = (E + 255) / 256;
  count_edges_k<<<eb, 256, 0, stream>>>(dst, cnt, E);
  scan_k<<<1, 1024, 0, stream>>>(cnt, row_ptr, dinv, N);
  fill_csr_k<<<eb, 256, 0, stream>>>(src, dst, row_ptr, cursor, csr_src, E);
  prep_k<<<NFM + 176 + 256, 256, 0, stream>>>(x, W1, W2, Wg, att_src, att_dst,
                                              xp, w1p, w2p, wgp, w_s, w_d, NFM);

  int mg64 = (N + 63) / 64;
  int ng4 = (N + 3) / 4;
  // layer 1
  mfma_gemm_k<4, HID, true><<<dim3(4, mg64), 256, 0, stream>>>(xp, w1p, tb, N);
  gcn_agg_k<false, true><<<ng4, 256, 0, stream>>>(tb, row_ptr, csr_src, dinv, b1,
                                                  h1p, nullptr, nullptr, nullptr, nullptr, N);
  // layer 2 (+ fused logits)
  mfma_gemm_k<8, HID, true><<<dim3(4, mg64), 256, 0, stream>>>(h1p, w2p, tb, N);
  gcn_agg_k<true, false><<<ng4, 256, 0, stream>>>(tb, row_ptr, csr_src, dinv, b2,
                                                  h2p, w_s, w_d, a_src4, a_dst4, N);
  // GAT
  mfma_gemm_k<8, NHEADS * HID, false><<<dim3(16, mg64), 256, 0, stream>>>(h2p, wgp, hgT, N);
  gat_agg_k<<<ng4, 256, 0, stream>>>(hgT, row_ptr, csr_src, a_src4, a_dst4, bg, h3, N);
  // pool + heads
  int pb = (N + POOL_CHUNK - 1) / POOL_CHUNK;
  pool_acc_k<<<pb, 256, 0, stream>>>(h3, batch, pooled, gcnt, N);
  head_k<<<1, 128, 0, stream>>>(pooled, gcnt, W_heads, b_heads, out);
}